// Round 12
// baseline (168.808 us; speedup 1.0000x reference)
//
#include <hip/hip_runtime.h>
#include <hip/hip_bf16.h>

// Problem dims
#define T_DIM 512
#define B_DIM 32
#define IN_DIM 256
#define H_DIM 256
#define K_DIM 10
#define TB 16384          // T*B
#define NKH 2560          // H*K
#define NPOW 3            // normalized power updates (v0 = rsum = M@1 is already 1 step)

typedef __attribute__((ext_vector_type(8))) short short8;
typedef __attribute__((ext_vector_type(4))) float f32x4;
typedef __attribute__((ext_vector_type(4), aligned(4))) int int4u;   // 4B-aligned dwordx4

#define GLOBAL_AS __attribute__((address_space(1)))
#define LDS_AS __attribute__((address_space(3)))

__device__ __forceinline__ float wave_sum64(float v) {
    #pragma unroll
    for (int off = 32; off > 0; off >>= 1) v += __shfl_xor(v, off, 64);
    return v;
}

__device__ __forceinline__ float bf_lo(int u) { return __int_as_float(u << 16); }
__device__ __forceinline__ float bf_hi(int u) { return __int_as_float(u & 0xffff0000); }

// ---- prep: weight normalize (blocks 0..639) + x norms/bf16 (blocks 640..4735) ----
__global__ __launch_bounds__(256) void prep_kernel(const float* __restrict__ w,
        const float* __restrict__ x, __hip_bfloat16* __restrict__ wb,
        __hip_bfloat16* __restrict__ wb2, float* __restrict__ xninfo,
        __hip_bfloat16* __restrict__ xb) {
    int wv = threadIdx.x >> 6, lane = threadIdx.x & 63;
    if (blockIdx.x < 640) {
        int row = blockIdx.x * 4 + wv;                 // 0..2559  (= h*10+k)
        const float* src = w + (size_t)row * IN_DIM;
        float v[4]; float s = 0.f;
        #pragma unroll
        for (int j = 0; j < 4; ++j) { v[j] = src[lane + 64 * j]; s += v[j] * v[j]; }
        s = wave_sum64(s);
        float inv = 1.f / fmaxf(sqrtf(s), 1e-4f);
        int h = row / K_DIM, k = row % K_DIM;
        __hip_bfloat16* d1 = wb + (size_t)row * IN_DIM;
        __hip_bfloat16* d2 = wb2 + (size_t)h * NKH + k * IN_DIM;
        #pragma unroll
        for (int j = 0; j < 4; ++j) {
            __hip_bfloat16 t = __float2bfloat16(v[j] * inv);
            d1[lane + 64 * j] = t;
            d2[lane + 64 * j] = t;
        }
    } else {
        int row = (blockIdx.x - 640) * 4 + wv;         // 0..16383
        const float* src = x + (size_t)row * IN_DIM;
        float v[4]; float s = 0.f;
        #pragma unroll
        for (int j = 0; j < 4; ++j) { v[j] = src[lane + 64 * j]; s += v[j] * v[j]; }
        s = wave_sum64(s);
        float nrm = sqrtf(s);
        if (lane == 0) { xninfo[2 * row] = nrm; xninfo[2 * row + 1] = 1.f / fmaxf(nrm, 1e-4f); }
        __hip_bfloat16* d = xb + (size_t)row * IN_DIM;
        #pragma unroll
        for (int j = 0; j < 4; ++j) d[lane + 64 * j] = __float2bfloat16(v[j]);
    }
}

// ---- merged: gemm_b (blocks 0..1279, 256x128 tile) + gram split-K (blocks 1280..1311) ----
// gemm: bmat[t*32+b][h*10+k] = kappa epilogue of xb @ wb^T; gram: Mpart[kz] partial tiles.
// 512 threads = 8 waves (4x2 of 64x64 sub-tiles); 2-phase double-buffered LDS (48 KB).
__global__ __launch_bounds__(512) void gemm_gram(const __hip_bfloat16* __restrict__ xb,
        const __hip_bfloat16* __restrict__ wb, const float* __restrict__ xninfo,
        __hip_bfloat16* __restrict__ bmat, const __hip_bfloat16* __restrict__ wb2,
        float* __restrict__ Mpart) {
    __shared__ __hip_bfloat16 As[2][8192];   // [256][32]
    __shared__ __hip_bfloat16 Bs[2][4096];   // [128][32]
    int tid = threadIdx.x;
    int wid = tid >> 6, lane = tid & 63;
    int wr = wid >> 1, wc = wid & 1;         // 4x2 waves over 256x128
    int seg = (lane >> 4) * 8;
    int rl = lane & 15;
    int col_l = lane & 15;
    int rseg = (lane >> 4) * 4;
    f32x4 acc[4][4] = {};

    if (blockIdx.x < 1280) {
        // -------- GEMM path: M=16384 (64 m-tiles), N=2560 (20 n-tiles) --------
        int m0 = (blockIdx.x & 63) * 256, n0 = (blockIdx.x >> 6) * 128;
        const __hip_bfloat16* ga0 = xb + (size_t)(m0 + (tid >> 2)) * IN_DIM + (tid & 3) * 8;
        const __hip_bfloat16* gb0 = wb + (size_t)(n0 + (tid >> 2)) * IN_DIM + (tid & 3) * 8;

        // prologue: stage step 0 into buf 0 (A: 2 issues, B: 1 issue per thread)
        __builtin_amdgcn_global_load_lds((const GLOBAL_AS void*)ga0,
            (LDS_AS void*)(&As[0][tid * 8]), 16, 0, 0);
        __builtin_amdgcn_global_load_lds((const GLOBAL_AS void*)(ga0 + (size_t)128 * IN_DIM),
            (LDS_AS void*)(&As[0][4096 + tid * 8]), 16, 0, 0);
        __builtin_amdgcn_global_load_lds((const GLOBAL_AS void*)gb0,
            (LDS_AS void*)(&Bs[0][tid * 8]), 16, 0, 0);
        __syncthreads();

        int cur = 0;
        for (int step = 0; step < 8; ++step) {
            if (step < 7) {
                int kbn = (step + 1) * 32;
                __builtin_amdgcn_global_load_lds((const GLOBAL_AS void*)(ga0 + kbn),
                    (LDS_AS void*)(&As[cur ^ 1][tid * 8]), 16, 0, 0);
                __builtin_amdgcn_global_load_lds((const GLOBAL_AS void*)(ga0 + (size_t)128 * IN_DIM + kbn),
                    (LDS_AS void*)(&As[cur ^ 1][4096 + tid * 8]), 16, 0, 0);
                __builtin_amdgcn_global_load_lds((const GLOBAL_AS void*)(gb0 + kbn),
                    (LDS_AS void*)(&Bs[cur ^ 1][tid * 8]), 16, 0, 0);
            }
            short8 a[4], b[4];
            #pragma unroll
            for (int m = 0; m < 4; ++m)
                a[m] = *(const short8*)(&As[cur][(wr * 64 + m * 16 + rl) * 32 + seg]);
            #pragma unroll
            for (int n = 0; n < 4; ++n)
                b[n] = *(const short8*)(&Bs[cur][(wc * 64 + n * 16 + rl) * 32 + seg]);
            #pragma unroll
            for (int m = 0; m < 4; ++m)
                #pragma unroll
                for (int n = 0; n < 4; ++n)
                    acc[m][n] = __builtin_amdgcn_mfma_f32_16x16x32_bf16(a[m], b[n], acc[m][n], 0, 0, 0);
            __syncthreads();
            cur ^= 1;
        }

        #pragma unroll
        for (int m = 0; m < 4; ++m) {
            int rbase = m0 + wr * 64 + m * 16 + rseg;
            float4 q0 = *(const float4*)(xninfo + 2 * rbase);
            float4 q1 = *(const float4*)(xninfo + 2 * rbase + 4);
            float nrm[4] = { q0.x, q0.z, q1.x, q1.z };
            float inv[4] = { q0.y, q0.w, q1.y, q1.w };
            #pragma unroll
            for (int n = 0; n < 4; ++n) {
                int col = n0 + wc * 64 + n * 16 + col_l;     // = h*10+k directly
                #pragma unroll
                for (int j = 0; j < 4; ++j) {
                    float bv = nrm[j] * __expf(0.4f * acc[m][n][j] * inv[j] - 0.4f);
                    bmat[(size_t)(rbase + j) * NKH + col] = __float2bfloat16(bv);
                }
            }
        }
    } else {
        // -------- GRAM path: 32 blocks: nt in {0,1}, kz in 0..15; tile 256x128, 5 K-steps --------
        int g = blockIdx.x - 1280;
        int nt = g & 1, kz = g >> 1;
        int n0 = nt * 128;
        const __hip_bfloat16* ga0 = wb2 + (size_t)(tid >> 2) * NKH + kz * 160 + (tid & 3) * 8;
        const __hip_bfloat16* gb0 = wb2 + (size_t)(n0 + (tid >> 2)) * NKH + kz * 160 + (tid & 3) * 8;

        __builtin_amdgcn_global_load_lds((const GLOBAL_AS void*)ga0,
            (LDS_AS void*)(&As[0][tid * 8]), 16, 0, 0);
        __builtin_amdgcn_global_load_lds((const GLOBAL_AS void*)(ga0 + (size_t)128 * NKH),
            (LDS_AS void*)(&As[0][4096 + tid * 8]), 16, 0, 0);
        __builtin_amdgcn_global_load_lds((const GLOBAL_AS void*)gb0,
            (LDS_AS void*)(&Bs[0][tid * 8]), 16, 0, 0);
        __syncthreads();

        int cur = 0;
        for (int ks = 0; ks < 5; ++ks) {
            if (ks < 4) {
                int kbn = (ks + 1) * 32;
                __builtin_amdgcn_global_load_lds((const GLOBAL_AS void*)(ga0 + kbn),
                    (LDS_AS void*)(&As[cur ^ 1][tid * 8]), 16, 0, 0);
                __builtin_amdgcn_global_load_lds((const GLOBAL_AS void*)(ga0 + (size_t)128 * NKH + kbn),
                    (LDS_AS void*)(&As[cur ^ 1][4096 + tid * 8]), 16, 0, 0);
                __builtin_amdgcn_global_load_lds((const GLOBAL_AS void*)(gb0 + kbn),
                    (LDS_AS void*)(&Bs[cur ^ 1][tid * 8]), 16, 0, 0);
            }
            short8 a[4], b[4];
            #pragma unroll
            for (int m = 0; m < 4; ++m)
                a[m] = *(const short8*)(&As[cur][(wr * 64 + m * 16 + rl) * 32 + seg]);
            #pragma unroll
            for (int n = 0; n < 4; ++n)
                b[n] = *(const short8*)(&Bs[cur][(wc * 64 + n * 16 + rl) * 32 + seg]);
            #pragma unroll
            for (int m = 0; m < 4; ++m)
                #pragma unroll
                for (int n = 0; n < 4; ++n)
                    acc[m][n] = __builtin_amdgcn_mfma_f32_16x16x32_bf16(a[m], b[n], acc[m][n], 0, 0, 0);
            __syncthreads();
            cur ^= 1;
        }

        float* dst = Mpart + (size_t)kz * 65536;
        #pragma unroll
        for (int m = 0; m < 4; ++m) {
            int rbase = wr * 64 + m * 16 + rseg;
            #pragma unroll
            for (int n = 0; n < 4; ++n) {
                int col = n0 + wc * 64 + n * 16 + col_l;
                #pragma unroll
                for (int j = 0; j < 4; ++j)
                    dst[(size_t)(rbase + j) * H_DIM + col] = acc[m][n][j];
            }
        }
    }
}

// ---- Gram finish: Mm = exp(0.4*sum_kz Mpart - 4), rsum[row] = row sum ----
__global__ __launch_bounds__(256) void gram_finish(const float* __restrict__ Mpart,
        float* __restrict__ Mm, float* __restrict__ rsum) {
    __shared__ float red[256];
    int r = blockIdx.x, c = threadIdx.x;
    float s = 0.f;
    #pragma unroll
    for (int kz = 0; kz < 16; ++kz)
        s += Mpart[(size_t)kz * 65536 + (size_t)r * H_DIM + c];
    float e = __expf(0.4f * s - 4.0f);
    Mm[(size_t)r * H_DIM + c] = e;
    red[c] = e;
    __syncthreads();
    #pragma unroll
    for (int st = 128; st > 0; st >>= 1) {
        if (c < st) red[c] += red[c + st];
        __syncthreads();
    }
    if (c == 0) rsum[r] = red[0];
}

// ---- shared power-iteration phase: fills vv (unit Perron vector), returns lam ----
__device__ __forceinline__ float power_phase(const float* __restrict__ Mm,
        const float* __restrict__ rsum, float* vv, float* red, int tid) {
    vv[tid] = rsum[tid];
    __syncthreads();
    float lam = 0.f;
    for (int it = 0; it <= NPOW; ++it) {
        float p = 0.f;
        #pragma unroll 8
        for (int g = 0; g < 256; ++g) p = fmaf(Mm[(size_t)g * 256 + tid], vv[g], p);
        __syncthreads();
        if (it < NPOW) {
            red[tid] = p * p;
            __syncthreads();
            #pragma unroll
            for (int st = 128; st > 0; st >>= 1) {
                if (tid < st) red[tid] += red[tid + st];
                __syncthreads();
            }
            float inv = rsqrtf(red[0]);
            __syncthreads();
            vv[tid] = p * inv;
            __syncthreads();
        } else {
            red[tid] = p * vv[tid];     // Rayleigh quotient (||v||=1)
            __syncthreads();
            #pragma unroll
            for (int st = 128; st > 0; st >>= 1) {
                if (tid < st) red[tid] += red[tid + st];
                __syncthreads();
            }
            lam = red[0];
            __syncthreads();
        }
    }
    return lam;
}

// ---- P2: E2 = E @ E, 16 blocks x 64x64 tile; embedded power phase; E from Mm on the fly ----
__global__ __launch_bounds__(256) void e2_kernel(const float* __restrict__ Mm,
        const float* __restrict__ rsum, float* __restrict__ E2g,
        __hip_bfloat16* __restrict__ e2b) {
    __shared__ __hip_bfloat16 EA[16384];   // [64][256] bf16, row-swizzled
    __shared__ __hip_bfloat16 EC[16384];
    __shared__ float vv[256];
    __shared__ float redl[256];
    int tid = threadIdx.x;
    int r0 = (blockIdx.x >> 2) * 64, c0 = (blockIdx.x & 3) * 64;
    float lam = power_phase(Mm, rsum, vv, redl, tid);
    float lm1 = lam - 1.f;
    char* pa = (char*)EA;
    char* pc = (char*)EC;
    for (int f = tid; f < 4096; f += 256) {
        int row = f >> 6, c4 = (f & 63) << 2;
        {
            int r = r0 + row;
            float4 mv = *(const float4*)(Mm + (size_t)r * 256 + c4);
            float vr = lm1 * vv[r];
            __hip_bfloat16 hb[4];
            hb[0] = __float2bfloat16(mv.x - ((r == c4 + 0) ? 1.f : 0.f) - vr * vv[c4 + 0]);
            hb[1] = __float2bfloat16(mv.y - ((r == c4 + 1) ? 1.f : 0.f) - vr * vv[c4 + 1]);
            hb[2] = __float2bfloat16(mv.z - ((r == c4 + 2) ? 1.f : 0.f) - vr * vv[c4 + 2]);
            hb[3] = __float2bfloat16(mv.w - ((r == c4 + 3) ? 1.f : 0.f) - vr * vv[c4 + 3]);
            *(short4*)(pa + row * 512 + ((c4 * 2) ^ ((row & 7) << 4))) = *(short4*)hb;
        }
        {
            int r = c0 + row;
            float4 mv = *(const float4*)(Mm + (size_t)r * 256 + c4);
            float vr = lm1 * vv[r];
            __hip_bfloat16 hb[4];
            hb[0] = __float2bfloat16(mv.x - ((r == c4 + 0) ? 1.f : 0.f) - vr * vv[c4 + 0]);
            hb[1] = __float2bfloat16(mv.y - ((r == c4 + 1) ? 1.f : 0.f) - vr * vv[c4 + 1]);
            hb[2] = __float2bfloat16(mv.z - ((r == c4 + 2) ? 1.f : 0.f) - vr * vv[c4 + 2]);
            hb[3] = __float2bfloat16(mv.w - ((r == c4 + 3) ? 1.f : 0.f) - vr * vv[c4 + 3]);
            *(short4*)(pc + row * 512 + ((c4 * 2) ^ ((row & 7) << 4))) = *(short4*)hb;
        }
    }
    __syncthreads();
    int wv = tid >> 6, lane = tid & 63;
    int rl = lane & 15, seg8 = (lane >> 4) * 8;
    f32x4 acc[4] = {};
    for (int kb = 0; kb < 256; kb += 32) {
        int row = wv * 16 + rl;
        short8 a = *(const short8*)(pa + row * 512 + (((kb + seg8) * 2) ^ ((rl & 7) << 4)));
        short8 b[4];
        #pragma unroll
        for (int n = 0; n < 4; ++n) {
            int rowb = n * 16 + rl;
            b[n] = *(const short8*)(pc + rowb * 512 + (((kb + seg8) * 2) ^ ((rl & 7) << 4)));
        }
        #pragma unroll
        for (int n = 0; n < 4; ++n)
            acc[n] = __builtin_amdgcn_mfma_f32_16x16x32_bf16(a, b[n], acc[n], 0, 0, 0);
    }
    int col_l = lane & 15, rseg = (lane >> 4) * 4;
    #pragma unroll
    for (int n = 0; n < 4; ++n) {
        #pragma unroll
        for (int j = 0; j < 4; ++j) {
            int r = r0 + wv * 16 + rseg + j;
            int c = c0 + n * 16 + col_l;
            size_t idx = (size_t)r * 256 + c;
            E2g[idx] = acc[n][j];
            e2b[idx] = __float2bfloat16(acc[n][j]);
        }
    }
}

// ---- P3: E3 = E @ E2; embedded power; lin = 1.5I - Mm/2 + (lm1/2+lfac) vv^T + 3/8 E2 - 5/16 E3
__global__ __launch_bounds__(256) void e3lin_kernel(const float* __restrict__ Mm,
        const float* __restrict__ rsum, const float* __restrict__ E2g,
        const __hip_bfloat16* __restrict__ e2b,
        float* __restrict__ lin, __hip_bfloat16* __restrict__ linb) {
    __shared__ __hip_bfloat16 EA[16384];   // [64][256] E rows, swizzled
    __shared__ __hip_bfloat16 EC[16384];   // [64][256] E2 rows (symmetric), swizzled
    __shared__ float vv[256];
    __shared__ float redl[256];
    int tid = threadIdx.x;
    int r0 = (blockIdx.x >> 2) * 64, c0 = (blockIdx.x & 3) * 64;
    float lam = power_phase(Mm, rsum, vv, redl, tid);
    float lm1 = lam - 1.f;
    float wfac = 0.5f * lm1 + (rsqrtf(lam) - 1.f);
    char* pa = (char*)EA;
    char* pc = (char*)EC;
    for (int f = tid; f < 4096; f += 256) {
        int row = f >> 6, c4 = (f & 63) << 2;
        int r = r0 + row;
        float4 mv = *(const float4*)(Mm + (size_t)r * 256 + c4);
        float vr = lm1 * vv[r];
        __hip_bfloat16 hb[4];
        hb[0] = __float2bfloat16(mv.x - ((r == c4 + 0) ? 1.f : 0.f) - vr * vv[c4 + 0]);
        hb[1] = __float2bfloat16(mv.y - ((r == c4 + 1) ? 1.f : 0.f) - vr * vv[c4 + 1]);
        hb[2] = __float2bfloat16(mv.z - ((r == c4 + 2) ? 1.f : 0.f) - vr * vv[c4 + 2]);
        hb[3] = __float2bfloat16(mv.w - ((r == c4 + 3) ? 1.f : 0.f) - vr * vv[c4 + 3]);
        *(short4*)(pa + row * 512 + ((c4 * 2) ^ ((row & 7) << 4))) = *(short4*)hb;
    }
    for (int f = tid; f < 2048; f += 256) {
        int row = f >> 5, c8 = (f & 31) << 3;
        short8 v8 = *(const short8*)(e2b + (size_t)(c0 + row) * 256 + c8);
        *(short8*)(pc + row * 512 + ((c8 * 2) ^ ((row & 7) << 4))) = v8;
    }
    __syncthreads();
    int wv = tid >> 6, lane = tid & 63;
    int rl = lane & 15, seg8 = (lane >> 4) * 8;
    f32x4 acc[4] = {};
    for (int kb = 0; kb < 256; kb += 32) {
        int row = wv * 16 + rl;
        short8 a = *(const short8*)(pa + row * 512 + (((kb + seg8) * 2) ^ ((rl & 7) << 4)));
        short8 b[4];
        #pragma unroll
        for (int n = 0; n < 4; ++n) {
            int rowb = n * 16 + rl;
            b[n] = *(const short8*)(pc + rowb * 512 + (((kb + seg8) * 2) ^ ((rl & 7) << 4)));
        }
        #pragma unroll
        for (int n = 0; n < 4; ++n)
            acc[n] = __builtin_amdgcn_mfma_f32_16x16x32_bf16(a, b[n], acc[n], 0, 0, 0);
    }
    int col_l = lane & 15, rseg = (lane >> 4) * 4;
    #pragma unroll
    for (int n = 0; n < 4; ++n) {
        #pragma unroll
        for (int j = 0; j < 4; ++j) {
            int r = r0 + wv * 16 + rseg + j;
            int c = c0 + n * 16 + col_l;
            size_t idx = (size_t)r * 256 + c;
            float lv = ((r == c) ? 1.5f : 0.f) - 0.5f * Mm[idx] + wfac * vv[r] * vv[c]
                     + 0.375f * E2g[idx] - 0.3125f * acc[n][j];
            lin[idx] = lv;
            linb[idx] = __float2bfloat16(lv);
        }
    }
}

// ---- megarec: 16 chunks x 32 outputs (warm-up 32 — W=16 FAILS: truncation error
// propagates through the recurrence and peaks at age~17; W=32 leaves ~1% rel, proven) ----
// bmat layout [t][b][h*10+k]: thread h reads 20 contiguous bytes per step (dwordx4 + dword).
__global__ __launch_bounds__(256) void megarec(const __hip_bfloat16* __restrict__ bmat,
        const __hip_bfloat16* __restrict__ linb, float* __restrict__ out1,
        float* __restrict__ part, float* __restrict__ hxT) {
    __shared__ __hip_bfloat16 c9t[8192];   // [32][256] bf16, row-swizzled (16 KB)
    int tid = threadIdx.x;
    int s = blockIdx.x >> 5;               // 0..15
    int b = blockIdx.x & 31;
    int h = tid;
    int tout0 = s * 32;
    int t0 = (s == 0) ? 0 : tout0 - 32;
    int t1 = tout0 + 32;
    char* c9p = (char*)c9t;
    float c[10] = {};
    float s9 = 0.f;
    int4u v0; int v1;
    {
        const char* bp = (const char*)bmat + ((size_t)(t0 * B_DIM + b) * NKH + h * 10) * 2;
        v0 = *(const int4u*)bp;
        v1 = *(const int*)(bp + 16);
    }
    for (int t = t0; t < t1; ++t) {
        int tn = (t + 1 < t1) ? t + 1 : t;
        const char* bq = (const char*)bmat + ((size_t)(tn * B_DIM + b) * NKH + h * 10) * 2;
        int4u w0 = *(const int4u*)bq;
        int w1 = *(const int*)(bq + 16);
        float bt[10];
        bt[0] = bf_lo(v0.x); bt[1] = bf_hi(v0.x);
        bt[2] = bf_lo(v0.y); bt[3] = bf_hi(v0.y);
        bt[4] = bf_lo(v0.z); bt[5] = bf_hi(v0.z);
        bt[6] = bf_lo(v0.w); bt[7] = bf_hi(v0.w);
        bt[8] = bf_lo(v1);   bt[9] = bf_hi(v1);
        #pragma unroll
        for (int j = 9; j >= 1; --j) c[j] = 0.5f * c[j] + c[j - 1] * bt[j];
        c[0] = 0.5f * c[0] + bt[0];
        if (t >= tout0) {
            int tt = t - tout0;
            *(__hip_bfloat16*)(c9p + tt * 512 + ((h * 2) ^ ((tt & 7) << 4))) = __float2bfloat16(c[9]);
            s9 += c[9];
        }
        v0 = w0; v1 = w1;
    }
    part[(size_t)(s * B_DIM + b) * H_DIM + h] = s9;
    if (s == 15) {
        float* hp = hxT + (size_t)(b * H_DIM + h) * K_DIM;
        #pragma unroll
        for (int k = 0; k < 10; ++k) hp[k] = c[k];
    }
    __syncthreads();
    // out1 GEMM: [32 tt] x [256 h] @ linb -> out1[tout0+tt][b][g]; wave wid owns g in [wid*64,+64)
    int wid = tid >> 6, lane = tid & 63;
    int rl = lane & 15, seg8 = (lane >> 4) * 8;
    int col_l = lane & 15, rseg = (lane >> 4) * 4;
    f32x4 acc[2][4] = {};
    for (int kb = 0; kb < 256; kb += 32) {
        short8 a[2];
        #pragma unroll
        for (int m = 0; m < 2; ++m) {
            int row = m * 16 + rl;
            a[m] = *(const short8*)(c9p + row * 512 + (((kb + seg8) * 2) ^ ((row & 7) << 4)));
        }
        short8 bf[4];
        #pragma unroll
        for (int n = 0; n < 4; ++n)
            bf[n] = *(const short8*)(linb + (size_t)(wid * 64 + n * 16 + rl) * 256 + kb + seg8);
        #pragma unroll
        for (int m = 0; m < 2; ++m)
            #pragma unroll
            for (int n = 0; n < 4; ++n)
                acc[m][n] = __builtin_amdgcn_mfma_f32_16x16x32_bf16(a[m], bf[n], acc[m][n], 0, 0, 0);
    }
    #pragma unroll
    for (int m = 0; m < 2; ++m) {
        #pragma unroll
        for (int n = 0; n < 4; ++n) {
            int g = wid * 64 + n * 16 + col_l;
            #pragma unroll
            for (int j = 0; j < 4; ++j) {
                int tt = m * 16 + rseg + j;
                out1[((size_t)(tout0 + tt) * B_DIM + b) * H_DIM + g] = acc[m][n][j];
            }
        }
    }
}

// ---- recout: mean over T of c9 (from part) then out0 = mean @ lin, one block per b ----
__global__ __launch_bounds__(256) void recout_kernel(const float* __restrict__ part,
        const float* __restrict__ lin, float* __restrict__ out0) {
    __shared__ float mrow[256];
    int b = blockIdx.x, tid = threadIdx.x;
    float s = 0.f;
    #pragma unroll
    for (int j = 0; j < 16; ++j) s += part[(size_t)(j * B_DIM + b) * H_DIM + tid];
    mrow[tid] = s * (1.f / T_DIM);
    __syncthreads();
    float acc = 0.f;
    #pragma unroll 8
    for (int h = 0; h < H_DIM; ++h) acc = fmaf(mrow[h], lin[(size_t)h * H_DIM + tid], acc);
    out0[b * H_DIM + tid] = acc;
}

extern "C" void kernel_launch(void* const* d_in, const int* in_sizes, int n_in,
                              void* d_out, int out_size, void* d_ws, size_t ws_size,
                              hipStream_t stream) {
    const float* x = (const float*)d_in[0];
    const float* w = (const float*)d_in[1];
    float* out0 = (float*)d_out;                       // B*H
    float* out1 = out0 + (size_t)B_DIM * H_DIM;        // T*B*H
    float* hxT  = out1 + (size_t)TB * H_DIM;           // B*H*K

    char* ws = (char*)d_ws;
    __hip_bfloat16* wb   = (__hip_bfloat16*)(ws + 0);          // 1,310,720
    __hip_bfloat16* wb2  = (__hip_bfloat16*)(ws + 1310720);    // 1,310,720
    float* xninfo        = (float*)(ws + 2621440);             //   131,072
    float* Mm            = (float*)(ws + 2752512);             //   262,144
    float* rsum          = (float*)(ws + 3014656);             //     1,024
    float* E2g           = (float*)(ws + 3015680);             //   262,144
    __hip_bfloat16* e2b  = (__hip_bfloat16*)(ws + 3277824);    //   131,072
    float* lin           = (float*)(ws + 3408896);             //   262,144
    __hip_bfloat16* linb = (__hip_bfloat16*)(ws + 3671040);    //   131,072
    float* part          = (float*)(ws + 3802112);             //   524,288 (16 chunks)
    float* Mpart         = (float*)(ws + 4326400);             // 4,194,304
    __hip_bfloat16* xb   = (__hip_bfloat16*)(ws + 8520704);    // 8,388,608
    __hip_bfloat16* bmat = (__hip_bfloat16*)(ws + 16909312);   // 83,886,080 -> ~100.8 MB

    prep_kernel<<<dim3(4736), dim3(256), 0, stream>>>(w, x, wb, wb2, xninfo, xb);
    gemm_gram<<<dim3(1312), dim3(512), 0, stream>>>(xb, wb, xninfo, bmat, wb2, Mpart);
    gram_finish<<<dim3(256), dim3(256), 0, stream>>>(Mpart, Mm, rsum);
    e2_kernel<<<dim3(16), dim3(256), 0, stream>>>(Mm, rsum, E2g, e2b);
    e3lin_kernel<<<dim3(16), dim3(256), 0, stream>>>(Mm, rsum, E2g, e2b, lin, linb);
    megarec<<<dim3(512), dim3(256), 0, stream>>>(bmat, linb, out1, part, hxT);
    recout_kernel<<<dim3(32), dim3(256), 0, stream>>>(part, lin, out0);
}

// Round 13
// 166.025 us; speedup vs baseline: 1.0168x; 1.0168x over previous
//
#include <hip/hip_runtime.h>
#include <hip/hip_bf16.h>

// Problem dims
#define T_DIM 512
#define B_DIM 32
#define IN_DIM 256
#define H_DIM 256
#define K_DIM 10
#define TB 16384          // T*B
#define NKH 2560          // H*K
#define NPOW 3            // normalized power updates (v0 = rsum = M@1 is already 1 step)

typedef __attribute__((ext_vector_type(8))) short short8;
typedef __attribute__((ext_vector_type(4))) float f32x4;
typedef __attribute__((ext_vector_type(4), aligned(4))) int int4u;   // 4B-aligned dwordx4

#define GLOBAL_AS __attribute__((address_space(1)))
#define LDS_AS __attribute__((address_space(3)))

__device__ __forceinline__ float wave_sum64(float v) {
    #pragma unroll
    for (int off = 32; off > 0; off >>= 1) v += __shfl_xor(v, off, 64);
    return v;
}

__device__ __forceinline__ float bf_lo(int u) { return __int_as_float(u << 16); }
__device__ __forceinline__ float bf_hi(int u) { return __int_as_float(u & 0xffff0000); }

// ---- prep: weight normalize (blocks 0..639) + x norms/bf16 (blocks 640..4735) ----
__global__ __launch_bounds__(256) void prep_kernel(const float* __restrict__ w,
        const float* __restrict__ x, __hip_bfloat16* __restrict__ wb,
        __hip_bfloat16* __restrict__ wb2, float* __restrict__ xninfo,
        __hip_bfloat16* __restrict__ xb) {
    int wv = threadIdx.x >> 6, lane = threadIdx.x & 63;
    if (blockIdx.x < 640) {
        int row = blockIdx.x * 4 + wv;                 // 0..2559  (= h*10+k)
        const float* src = w + (size_t)row * IN_DIM;
        float v[4]; float s = 0.f;
        #pragma unroll
        for (int j = 0; j < 4; ++j) { v[j] = src[lane + 64 * j]; s += v[j] * v[j]; }
        s = wave_sum64(s);
        float inv = 1.f / fmaxf(sqrtf(s), 1e-4f);
        int h = row / K_DIM, k = row % K_DIM;
        __hip_bfloat16* d1 = wb + (size_t)row * IN_DIM;
        __hip_bfloat16* d2 = wb2 + (size_t)h * NKH + k * IN_DIM;
        #pragma unroll
        for (int j = 0; j < 4; ++j) {
            __hip_bfloat16 t = __float2bfloat16(v[j] * inv);
            d1[lane + 64 * j] = t;
            d2[lane + 64 * j] = t;
        }
    } else {
        int row = (blockIdx.x - 640) * 4 + wv;         // 0..16383
        const float* src = x + (size_t)row * IN_DIM;
        float v[4]; float s = 0.f;
        #pragma unroll
        for (int j = 0; j < 4; ++j) { v[j] = src[lane + 64 * j]; s += v[j] * v[j]; }
        s = wave_sum64(s);
        float nrm = sqrtf(s);
        if (lane == 0) { xninfo[2 * row] = nrm; xninfo[2 * row + 1] = 1.f / fmaxf(nrm, 1e-4f); }
        __hip_bfloat16* d = xb + (size_t)row * IN_DIM;
        #pragma unroll
        for (int j = 0; j < 4; ++j) d[lane + 64 * j] = __float2bfloat16(v[j]);
    }
}

// ---- merged gemm (blocks 0..2559, 128x128 tile) + gram split-K (blocks 2560..2623) ----
// KEY: MFMA operands SWAPPED (mfma(P,Q)=P*Q^T): acc[m][n]=mfma(b[n],a[m]) holds the
// TRANSPOSED tile -> lane's 4 accum j-values are 4 CONSECUTIVE n' columns of bmat
// -> one 8B short4 store per (m,n) instead of 64 scattered 2B stores per thread.
__global__ __launch_bounds__(256) void gemm_gram(const __hip_bfloat16* __restrict__ xb,
        const __hip_bfloat16* __restrict__ wb, const float* __restrict__ xninfo,
        __hip_bfloat16* __restrict__ bmat, const __hip_bfloat16* __restrict__ wb2,
        float* __restrict__ Mpart) {
    __shared__ __hip_bfloat16 As[2][4096];   // [128][32]
    __shared__ __hip_bfloat16 Bs[2][4096];
    int tid = threadIdx.x;
    int wid = tid >> 6, lane = tid & 63;
    int wr = wid >> 1, wc = wid & 1;
    int srow = tid >> 2;                 // staging row within 64-half
    int scol = (tid & 3) * 8;
    int seg = (lane >> 4) * 8;
    int rl = lane & 15;
    int col_l = lane & 15;
    int rseg = (lane >> 4) * 4;
    f32x4 acc[4][4] = {};

    if (blockIdx.x < 2560) {
        // -------- GEMM: M=16384 (128 m-tiles), N=2560 (20 n-tiles) --------
        int m0 = (blockIdx.x & 127) * 128, n0 = (blockIdx.x >> 7) * 128;
        const __hip_bfloat16* ga0 = xb + (size_t)(m0 + srow) * IN_DIM + scol;
        const __hip_bfloat16* gb0 = wb + (size_t)(n0 + srow) * IN_DIM + scol;

        #pragma unroll
        for (int half = 0; half < 2; ++half) {
            __builtin_amdgcn_global_load_lds((const GLOBAL_AS void*)(ga0 + half * 64 * IN_DIM),
                (LDS_AS void*)(&As[0][half * 2048 + wid * 512]), 16, 0, 0);
            __builtin_amdgcn_global_load_lds((const GLOBAL_AS void*)(gb0 + half * 64 * IN_DIM),
                (LDS_AS void*)(&Bs[0][half * 2048 + wid * 512]), 16, 0, 0);
        }
        __syncthreads();

        int cur = 0;
        for (int step = 0; step < 8; ++step) {
            if (step < 7) {
                int kbn = (step + 1) * 32;
                #pragma unroll
                for (int half = 0; half < 2; ++half) {
                    __builtin_amdgcn_global_load_lds((const GLOBAL_AS void*)(ga0 + half * 64 * IN_DIM + kbn),
                        (LDS_AS void*)(&As[cur ^ 1][half * 2048 + wid * 512]), 16, 0, 0);
                    __builtin_amdgcn_global_load_lds((const GLOBAL_AS void*)(gb0 + half * 64 * IN_DIM + kbn),
                        (LDS_AS void*)(&Bs[cur ^ 1][half * 2048 + wid * 512]), 16, 0, 0);
                }
            }
            short8 a[4], b[4];
            #pragma unroll
            for (int m = 0; m < 4; ++m)
                a[m] = *(const short8*)(&As[cur][(wr * 64 + m * 16 + rl) * 32 + seg]);
            #pragma unroll
            for (int n = 0; n < 4; ++n)
                b[n] = *(const short8*)(&Bs[cur][(wc * 64 + n * 16 + rl) * 32 + seg]);
            #pragma unroll
            for (int m = 0; m < 4; ++m)
                #pragma unroll
                for (int n = 0; n < 4; ++n)
                    acc[m][n] = __builtin_amdgcn_mfma_f32_16x16x32_bf16(b[n], a[m], acc[m][n], 0, 0, 0);
            __syncthreads();
            cur ^= 1;
        }

        // epilogue: transposed tile -> lane: col m_g = m0+wr*64+m*16+col_l (x-row),
        // rows n' = n0+wc*64+n*16+rseg+j (4 consecutive) -> short4 store
        #pragma unroll
        for (int m = 0; m < 4; ++m) {
            int mg = m0 + wr * 64 + m * 16 + col_l;
            float2 xq = *(const float2*)(xninfo + 2 * mg);
            float nrm = xq.x, inv = xq.y;
            #pragma unroll
            for (int n = 0; n < 4; ++n) {
                int np = n0 + wc * 64 + n * 16 + rseg;
                __hip_bfloat16 hb[4];
                #pragma unroll
                for (int j = 0; j < 4; ++j)
                    hb[j] = __float2bfloat16(nrm * __expf(0.4f * acc[m][n][j] * inv - 0.4f));
                *(short4*)((char*)bmat + ((size_t)mg * NKH + np) * 2) = *(short4*)hb;
            }
        }
    } else {
        // -------- GRAM: 64 blocks: g = bid-2560; kz=g&15, mi=(g>>4)&1, ni=g>>5 --------
        int g = blockIdx.x - 2560;
        int kz = g & 15, mi = (g >> 4) & 1, ni = g >> 5;
        int m0 = mi * 128, n0 = ni * 128;
        const __hip_bfloat16* ga0 = wb2 + (size_t)(m0 + srow) * NKH + kz * 160 + scol;
        const __hip_bfloat16* gb0 = wb2 + (size_t)(n0 + srow) * NKH + kz * 160 + scol;

        #pragma unroll
        for (int half = 0; half < 2; ++half) {
            __builtin_amdgcn_global_load_lds((const GLOBAL_AS void*)(ga0 + half * 64 * NKH),
                (LDS_AS void*)(&As[0][half * 2048 + wid * 512]), 16, 0, 0);
            __builtin_amdgcn_global_load_lds((const GLOBAL_AS void*)(gb0 + half * 64 * NKH),
                (LDS_AS void*)(&Bs[0][half * 2048 + wid * 512]), 16, 0, 0);
        }
        __syncthreads();

        int cur = 0;
        for (int ks = 0; ks < 5; ++ks) {
            if (ks < 4) {
                int kbn = (ks + 1) * 32;
                #pragma unroll
                for (int half = 0; half < 2; ++half) {
                    __builtin_amdgcn_global_load_lds((const GLOBAL_AS void*)(ga0 + half * 64 * NKH + kbn),
                        (LDS_AS void*)(&As[cur ^ 1][half * 2048 + wid * 512]), 16, 0, 0);
                    __builtin_amdgcn_global_load_lds((const GLOBAL_AS void*)(gb0 + half * 64 * NKH + kbn),
                        (LDS_AS void*)(&Bs[cur ^ 1][half * 2048 + wid * 512]), 16, 0, 0);
                }
            }
            short8 a[4], b[4];
            #pragma unroll
            for (int m = 0; m < 4; ++m)
                a[m] = *(const short8*)(&As[cur][(wr * 64 + m * 16 + rl) * 32 + seg]);
            #pragma unroll
            for (int n = 0; n < 4; ++n)
                b[n] = *(const short8*)(&Bs[cur][(wc * 64 + n * 16 + rl) * 32 + seg]);
            #pragma unroll
            for (int m = 0; m < 4; ++m)
                #pragma unroll
                for (int n = 0; n < 4; ++n)
                    acc[m][n] = __builtin_amdgcn_mfma_f32_16x16x32_bf16(b[n], a[m], acc[m][n], 0, 0, 0);
            __syncthreads();
            cur ^= 1;
        }

        // transposed tile -> float4 store: row = m-side col per lane, 4 consecutive n'
        float* dst = Mpart + (size_t)kz * 65536;
        #pragma unroll
        for (int m = 0; m < 4; ++m) {
            int mg = m0 + wr * 64 + m * 16 + col_l;
            #pragma unroll
            for (int n = 0; n < 4; ++n) {
                int np = n0 + wc * 64 + n * 16 + rseg;
                float4 fv = { acc[m][n][0], acc[m][n][1], acc[m][n][2], acc[m][n][3] };
                *(float4*)(dst + (size_t)mg * H_DIM + np) = fv;
            }
        }
    }
}

// ---- Gram finish: Mm = exp(0.4*sum_kz Mpart - 4), rsum[row] = row sum ----
__global__ __launch_bounds__(256) void gram_finish(const float* __restrict__ Mpart,
        float* __restrict__ Mm, float* __restrict__ rsum) {
    __shared__ float red[256];
    int r = blockIdx.x, c = threadIdx.x;
    float s = 0.f;
    #pragma unroll
    for (int kz = 0; kz < 16; ++kz)
        s += Mpart[(size_t)kz * 65536 + (size_t)r * H_DIM + c];
    float e = __expf(0.4f * s - 4.0f);
    Mm[(size_t)r * H_DIM + c] = e;
    red[c] = e;
    __syncthreads();
    #pragma unroll
    for (int st = 128; st > 0; st >>= 1) {
        if (c < st) red[c] += red[c + st];
        __syncthreads();
    }
    if (c == 0) rsum[r] = red[0];
}

// ---- shared power-iteration phase: fills vv (unit Perron vector), returns lam ----
__device__ __forceinline__ float power_phase(const float* __restrict__ Mm,
        const float* __restrict__ rsum, float* vv, float* red, int tid) {
    vv[tid] = rsum[tid];
    __syncthreads();
    float lam = 0.f;
    for (int it = 0; it <= NPOW; ++it) {
        float p = 0.f;
        #pragma unroll 8
        for (int g = 0; g < 256; ++g) p = fmaf(Mm[(size_t)g * 256 + tid], vv[g], p);
        __syncthreads();
        if (it < NPOW) {
            red[tid] = p * p;
            __syncthreads();
            #pragma unroll
            for (int st = 128; st > 0; st >>= 1) {
                if (tid < st) red[tid] += red[tid + st];
                __syncthreads();
            }
            float inv = rsqrtf(red[0]);
            __syncthreads();
            vv[tid] = p * inv;
            __syncthreads();
        } else {
            red[tid] = p * vv[tid];     // Rayleigh quotient (||v||=1)
            __syncthreads();
            #pragma unroll
            for (int st = 128; st > 0; st >>= 1) {
                if (tid < st) red[tid] += red[tid + st];
                __syncthreads();
            }
            lam = red[0];
            __syncthreads();
        }
    }
    return lam;
}

// ---- P2: E2 = E @ E, 16 blocks x 64x64 tile; embedded power phase; E from Mm on the fly ----
__global__ __launch_bounds__(256) void e2_kernel(const float* __restrict__ Mm,
        const float* __restrict__ rsum, float* __restrict__ E2g,
        __hip_bfloat16* __restrict__ e2b) {
    __shared__ __hip_bfloat16 EA[16384];   // [64][256] bf16, row-swizzled
    __shared__ __hip_bfloat16 EC[16384];
    __shared__ float vv[256];
    __shared__ float redl[256];
    int tid = threadIdx.x;
    int r0 = (blockIdx.x >> 2) * 64, c0 = (blockIdx.x & 3) * 64;
    float lam = power_phase(Mm, rsum, vv, redl, tid);
    float lm1 = lam - 1.f;
    char* pa = (char*)EA;
    char* pc = (char*)EC;
    for (int f = tid; f < 4096; f += 256) {
        int row = f >> 6, c4 = (f & 63) << 2;
        {
            int r = r0 + row;
            float4 mv = *(const float4*)(Mm + (size_t)r * 256 + c4);
            float vr = lm1 * vv[r];
            __hip_bfloat16 hb[4];
            hb[0] = __float2bfloat16(mv.x - ((r == c4 + 0) ? 1.f : 0.f) - vr * vv[c4 + 0]);
            hb[1] = __float2bfloat16(mv.y - ((r == c4 + 1) ? 1.f : 0.f) - vr * vv[c4 + 1]);
            hb[2] = __float2bfloat16(mv.z - ((r == c4 + 2) ? 1.f : 0.f) - vr * vv[c4 + 2]);
            hb[3] = __float2bfloat16(mv.w - ((r == c4 + 3) ? 1.f : 0.f) - vr * vv[c4 + 3]);
            *(short4*)(pa + row * 512 + ((c4 * 2) ^ ((row & 7) << 4))) = *(short4*)hb;
        }
        {
            int r = c0 + row;
            float4 mv = *(const float4*)(Mm + (size_t)r * 256 + c4);
            float vr = lm1 * vv[r];
            __hip_bfloat16 hb[4];
            hb[0] = __float2bfloat16(mv.x - ((r == c4 + 0) ? 1.f : 0.f) - vr * vv[c4 + 0]);
            hb[1] = __float2bfloat16(mv.y - ((r == c4 + 1) ? 1.f : 0.f) - vr * vv[c4 + 1]);
            hb[2] = __float2bfloat16(mv.z - ((r == c4 + 2) ? 1.f : 0.f) - vr * vv[c4 + 2]);
            hb[3] = __float2bfloat16(mv.w - ((r == c4 + 3) ? 1.f : 0.f) - vr * vv[c4 + 3]);
            *(short4*)(pc + row * 512 + ((c4 * 2) ^ ((row & 7) << 4))) = *(short4*)hb;
        }
    }
    __syncthreads();
    int wv = tid >> 6, lane = tid & 63;
    int rl = lane & 15, seg8 = (lane >> 4) * 8;
    f32x4 acc[4] = {};
    for (int kb = 0; kb < 256; kb += 32) {
        int row = wv * 16 + rl;
        short8 a = *(const short8*)(pa + row * 512 + (((kb + seg8) * 2) ^ ((rl & 7) << 4)));
        short8 b[4];
        #pragma unroll
        for (int n = 0; n < 4; ++n) {
            int rowb = n * 16 + rl;
            b[n] = *(const short8*)(pc + rowb * 512 + (((kb + seg8) * 2) ^ ((rl & 7) << 4)));
        }
        #pragma unroll
        for (int n = 0; n < 4; ++n)
            acc[n] = __builtin_amdgcn_mfma_f32_16x16x32_bf16(a, b[n], acc[n], 0, 0, 0);
    }
    int col_l = lane & 15, rseg = (lane >> 4) * 4;
    #pragma unroll
    for (int n = 0; n < 4; ++n) {
        #pragma unroll
        for (int j = 0; j < 4; ++j) {
            int r = r0 + wv * 16 + rseg + j;
            int c = c0 + n * 16 + col_l;
            size_t idx = (size_t)r * 256 + c;
            E2g[idx] = acc[n][j];
            e2b[idx] = __float2bfloat16(acc[n][j]);
        }
    }
}

// ---- P3: E3 = E @ E2; embedded power; lin = 1.5I - Mm/2 + (lm1/2+lfac) vv^T + 3/8 E2 - 5/16 E3
__global__ __launch_bounds__(256) void e3lin_kernel(const float* __restrict__ Mm,
        const float* __restrict__ rsum, const float* __restrict__ E2g,
        const __hip_bfloat16* __restrict__ e2b,
        float* __restrict__ lin, __hip_bfloat16* __restrict__ linb) {
    __shared__ __hip_bfloat16 EA[16384];   // [64][256] E rows, swizzled
    __shared__ __hip_bfloat16 EC[16384];   // [64][256] E2 rows (symmetric), swizzled
    __shared__ float vv[256];
    __shared__ float redl[256];
    int tid = threadIdx.x;
    int r0 = (blockIdx.x >> 2) * 64, c0 = (blockIdx.x & 3) * 64;
    float lam = power_phase(Mm, rsum, vv, redl, tid);
    float lm1 = lam - 1.f;
    float wfac = 0.5f * lm1 + (rsqrtf(lam) - 1.f);
    char* pa = (char*)EA;
    char* pc = (char*)EC;
    for (int f = tid; f < 4096; f += 256) {
        int row = f >> 6, c4 = (f & 63) << 2;
        int r = r0 + row;
        float4 mv = *(const float4*)(Mm + (size_t)r * 256 + c4);
        float vr = lm1 * vv[r];
        __hip_bfloat16 hb[4];
        hb[0] = __float2bfloat16(mv.x - ((r == c4 + 0) ? 1.f : 0.f) - vr * vv[c4 + 0]);
        hb[1] = __float2bfloat16(mv.y - ((r == c4 + 1) ? 1.f : 0.f) - vr * vv[c4 + 1]);
        hb[2] = __float2bfloat16(mv.z - ((r == c4 + 2) ? 1.f : 0.f) - vr * vv[c4 + 2]);
        hb[3] = __float2bfloat16(mv.w - ((r == c4 + 3) ? 1.f : 0.f) - vr * vv[c4 + 3]);
        *(short4*)(pa + row * 512 + ((c4 * 2) ^ ((row & 7) << 4))) = *(short4*)hb;
    }
    for (int f = tid; f < 2048; f += 256) {
        int row = f >> 5, c8 = (f & 31) << 3;
        short8 v8 = *(const short8*)(e2b + (size_t)(c0 + row) * 256 + c8);
        *(short8*)(pc + row * 512 + ((c8 * 2) ^ ((row & 7) << 4))) = v8;
    }
    __syncthreads();
    int wv = tid >> 6, lane = tid & 63;
    int rl = lane & 15, seg8 = (lane >> 4) * 8;
    f32x4 acc[4] = {};
    for (int kb = 0; kb < 256; kb += 32) {
        int row = wv * 16 + rl;
        short8 a = *(const short8*)(pa + row * 512 + (((kb + seg8) * 2) ^ ((rl & 7) << 4)));
        short8 b[4];
        #pragma unroll
        for (int n = 0; n < 4; ++n) {
            int rowb = n * 16 + rl;
            b[n] = *(const short8*)(pc + rowb * 512 + (((kb + seg8) * 2) ^ ((rl & 7) << 4)));
        }
        #pragma unroll
        for (int n = 0; n < 4; ++n)
            acc[n] = __builtin_amdgcn_mfma_f32_16x16x32_bf16(a, b[n], acc[n], 0, 0, 0);
    }
    int col_l = lane & 15, rseg = (lane >> 4) * 4;
    #pragma unroll
    for (int n = 0; n < 4; ++n) {
        #pragma unroll
        for (int j = 0; j < 4; ++j) {
            int r = r0 + wv * 16 + rseg + j;
            int c = c0 + n * 16 + col_l;
            size_t idx = (size_t)r * 256 + c;
            float lv = ((r == c) ? 1.5f : 0.f) - 0.5f * Mm[idx] + wfac * vv[r] * vv[c]
                     + 0.375f * E2g[idx] - 0.3125f * acc[n][j];
            lin[idx] = lv;
            linb[idx] = __float2bfloat16(lv);
        }
    }
}

// ---- megarec: 16 chunks x 32 outputs (warm-up 32; W=16 FAILS — truncation error
// propagates through the recurrence, peaks at age~17) + fused out1 = c9 @ linb ----
__global__ __launch_bounds__(256) void megarec(const __hip_bfloat16* __restrict__ bmat,
        const __hip_bfloat16* __restrict__ linb, float* __restrict__ out1,
        float* __restrict__ part, float* __restrict__ hxT) {
    __shared__ __hip_bfloat16 c9t[8192];   // [32][256] bf16, row-swizzled (16 KB)
    int tid = threadIdx.x;
    int s = blockIdx.x >> 5;               // 0..15
    int b = blockIdx.x & 31;
    int h = tid;
    int tout0 = s * 32;
    int t0 = (s == 0) ? 0 : tout0 - 32;
    int t1 = tout0 + 32;
    char* c9p = (char*)c9t;
    float c[10] = {};
    float s9 = 0.f;
    int4u v0; int v1;
    {
        const char* bp = (const char*)bmat + ((size_t)(t0 * B_DIM + b) * NKH + h * 10) * 2;
        v0 = *(const int4u*)bp;
        v1 = *(const int*)(bp + 16);
    }
    for (int t = t0; t < t1; ++t) {
        int tn = (t + 1 < t1) ? t + 1 : t;
        const char* bq = (const char*)bmat + ((size_t)(tn * B_DIM + b) * NKH + h * 10) * 2;
        int4u w0 = *(const int4u*)bq;
        int w1 = *(const int*)(bq + 16);
        float bt[10];
        bt[0] = bf_lo(v0.x); bt[1] = bf_hi(v0.x);
        bt[2] = bf_lo(v0.y); bt[3] = bf_hi(v0.y);
        bt[4] = bf_lo(v0.z); bt[5] = bf_hi(v0.z);
        bt[6] = bf_lo(v0.w); bt[7] = bf_hi(v0.w);
        bt[8] = bf_lo(v1);   bt[9] = bf_hi(v1);
        #pragma unroll
        for (int j = 9; j >= 1; --j) c[j] = 0.5f * c[j] + c[j - 1] * bt[j];
        c[0] = 0.5f * c[0] + bt[0];
        if (t >= tout0) {
            int tt = t - tout0;
            *(__hip_bfloat16*)(c9p + tt * 512 + ((h * 2) ^ ((tt & 7) << 4))) = __float2bfloat16(c[9]);
            s9 += c[9];
        }
        v0 = w0; v1 = w1;
    }
    part[(size_t)(s * B_DIM + b) * H_DIM + h] = s9;
    if (s == 15) {
        float* hp = hxT + (size_t)(b * H_DIM + h) * K_DIM;
        #pragma unroll
        for (int k = 0; k < 10; ++k) hp[k] = c[k];
    }
    __syncthreads();
    // out1 GEMM: [32 tt] x [256 h] @ linb -> out1[tout0+tt][b][g]; wave wid owns g in [wid*64,+64)
    int wid = tid >> 6, lane = tid & 63;
    int rl = lane & 15, seg8 = (lane >> 4) * 8;
    int col_l = lane & 15, rseg = (lane >> 4) * 4;
    f32x4 acc[2][4] = {};
    for (int kb = 0; kb < 256; kb += 32) {
        short8 a[2];
        #pragma unroll
        for (int m = 0; m < 2; ++m) {
            int row = m * 16 + rl;
            a[m] = *(const short8*)(c9p + row * 512 + (((kb + seg8) * 2) ^ ((row & 7) << 4)));
        }
        short8 bf[4];
        #pragma unroll
        for (int n = 0; n < 4; ++n)
            bf[n] = *(const short8*)(linb + (size_t)(wid * 64 + n * 16 + rl) * 256 + kb + seg8);
        #pragma unroll
        for (int m = 0; m < 2; ++m)
            #pragma unroll
            for (int n = 0; n < 4; ++n)
                acc[m][n] = __builtin_amdgcn_mfma_f32_16x16x32_bf16(a[m], bf[n], acc[m][n], 0, 0, 0);
    }
    #pragma unroll
    for (int m = 0; m < 2; ++m) {
        #pragma unroll
        for (int n = 0; n < 4; ++n) {
            int g = wid * 64 + n * 16 + col_l;
            #pragma unroll
            for (int j = 0; j < 4; ++j) {
                int tt = m * 16 + rseg + j;
                out1[((size_t)(tout0 + tt) * B_DIM + b) * H_DIM + g] = acc[m][n][j];
            }
        }
    }
}

// ---- recout: mean over T of c9 (from part) then out0 = mean @ lin, one block per b ----
__global__ __launch_bounds__(256) void recout_kernel(const float* __restrict__ part,
        const float* __restrict__ lin, float* __restrict__ out0) {
    __shared__ float mrow[256];
    int b = blockIdx.x, tid = threadIdx.x;
    float s = 0.f;
    #pragma unroll
    for (int j = 0; j < 16; ++j) s += part[(size_t)(j * B_DIM + b) * H_DIM + tid];
    mrow[tid] = s * (1.f / T_DIM);
    __syncthreads();
    float acc = 0.f;
    #pragma unroll 8
    for (int h = 0; h < H_DIM; ++h) acc = fmaf(mrow[h], lin[(size_t)h * H_DIM + tid], acc);
    out0[b * H_DIM + tid] = acc;
}

extern "C" void kernel_launch(void* const* d_in, const int* in_sizes, int n_in,
                              void* d_out, int out_size, void* d_ws, size_t ws_size,
                              hipStream_t stream) {
    const float* x = (const float*)d_in[0];
    const float* w = (const float*)d_in[1];
    float* out0 = (float*)d_out;                       // B*H
    float* out1 = out0 + (size_t)B_DIM * H_DIM;        // T*B*H
    float* hxT  = out1 + (size_t)TB * H_DIM;           // B*H*K

    char* ws = (char*)d_ws;
    __hip_bfloat16* wb   = (__hip_bfloat16*)(ws + 0);          // 1,310,720
    __hip_bfloat16* wb2  = (__hip_bfloat16*)(ws + 1310720);    // 1,310,720
    float* xninfo        = (float*)(ws + 2621440);             //   131,072
    float* Mm            = (float*)(ws + 2752512);             //   262,144
    float* rsum          = (float*)(ws + 3014656);             //     1,024
    float* E2g           = (float*)(ws + 3015680);             //   262,144
    __hip_bfloat16* e2b  = (__hip_bfloat16*)(ws + 3277824);    //   131,072
    float* lin           = (float*)(ws + 3408896);             //   262,144
    __hip_bfloat16* linb = (__hip_bfloat16*)(ws + 3671040);    //   131,072
    float* part          = (float*)(ws + 3802112);             //   524,288 (16 chunks)
    float* Mpart         = (float*)(ws + 4326400);             // 4,194,304
    __hip_bfloat16* xb   = (__hip_bfloat16*)(ws + 8520704);    // 8,388,608
    __hip_bfloat16* bmat = (__hip_bfloat16*)(ws + 16909312);   // 83,886,080 -> ~100.8 MB

    prep_kernel<<<dim3(4736), dim3(256), 0, stream>>>(w, x, wb, wb2, xninfo, xb);
    gemm_gram<<<dim3(2624), dim3(256), 0, stream>>>(xb, wb, xninfo, bmat, wb2, Mpart);
    gram_finish<<<dim3(256), dim3(256), 0, stream>>>(Mpart, Mm, rsum);
    e2_kernel<<<dim3(16), dim3(256), 0, stream>>>(Mm, rsum, E2g, e2b);
    e3lin_kernel<<<dim3(16), dim3(256), 0, stream>>>(Mm, rsum, E2g, e2b, lin, linb);
    megarec<<<dim3(512), dim3(256), 0, stream>>>(bmat, linb, out1, part, hxT);
    recout_kernel<<<dim3(32), dim3(256), 0, stream>>>(part, lin, out0);
}

// Round 14
// 159.377 us; speedup vs baseline: 1.0592x; 1.0417x over previous
//
#include <hip/hip_runtime.h>
#include <hip/hip_bf16.h>

// Problem dims
#define T_DIM 512
#define B_DIM 32
#define IN_DIM 256
#define H_DIM 256
#define K_DIM 10
#define TB 16384          // T*B
#define NKH 2560          // H*K
#define NPOW 3            // normalized power updates (v0 = rsum = M@1 is already 1 step)

typedef __attribute__((ext_vector_type(8))) short short8;
typedef __attribute__((ext_vector_type(4))) float f32x4;
typedef __attribute__((ext_vector_type(4), aligned(4))) int int4u;   // 4B-aligned dwordx4

#define GLOBAL_AS __attribute__((address_space(1)))
#define LDS_AS __attribute__((address_space(3)))

__device__ __forceinline__ float wave_sum64(float v) {
    #pragma unroll
    for (int off = 32; off > 0; off >>= 1) v += __shfl_xor(v, off, 64);
    return v;
}

__device__ __forceinline__ float bf_lo(int u) { return __int_as_float(u << 16); }
__device__ __forceinline__ float bf_hi(int u) { return __int_as_float(u & 0xffff0000); }

// ---- prep: weight normalize (blocks 0..639) + x norms/bf16 (blocks 640..4735) ----
// wb bf16 [h*10+k][256] (original row order); wb2 bf16 [h][k*256+i] (for gram)
__global__ __launch_bounds__(256) void prep_kernel(const float* __restrict__ w,
        const float* __restrict__ x, __hip_bfloat16* __restrict__ wb,
        __hip_bfloat16* __restrict__ wb2, float* __restrict__ xninfo,
        __hip_bfloat16* __restrict__ xb) {
    int wv = threadIdx.x >> 6, lane = threadIdx.x & 63;
    if (blockIdx.x < 640) {
        int row = blockIdx.x * 4 + wv;                 // 0..2559  (= h*10+k)
        const float* src = w + (size_t)row * IN_DIM;
        float v[4]; float s = 0.f;
        #pragma unroll
        for (int j = 0; j < 4; ++j) { v[j] = src[lane + 64 * j]; s += v[j] * v[j]; }
        s = wave_sum64(s);
        float inv = 1.f / fmaxf(sqrtf(s), 1e-4f);
        int h = row / K_DIM, k = row % K_DIM;
        __hip_bfloat16* d1 = wb + (size_t)row * IN_DIM;
        __hip_bfloat16* d2 = wb2 + (size_t)h * NKH + k * IN_DIM;
        #pragma unroll
        for (int j = 0; j < 4; ++j) {
            __hip_bfloat16 t = __float2bfloat16(v[j] * inv);
            d1[lane + 64 * j] = t;
            d2[lane + 64 * j] = t;
        }
    } else {
        int row = (blockIdx.x - 640) * 4 + wv;         // 0..16383
        const float* src = x + (size_t)row * IN_DIM;
        float v[4]; float s = 0.f;
        #pragma unroll
        for (int j = 0; j < 4; ++j) { v[j] = src[lane + 64 * j]; s += v[j] * v[j]; }
        s = wave_sum64(s);
        float nrm = sqrtf(s);
        if (lane == 0) { xninfo[2 * row] = nrm; xninfo[2 * row + 1] = 1.f / fmaxf(nrm, 1e-4f); }
        __hip_bfloat16* d = xb + (size_t)row * IN_DIM;
        #pragma unroll
        for (int j = 0; j < 4; ++j) d[lane + 64 * j] = __float2bfloat16(v[j]);
    }
}

// ---- big GEMM via bf16 MFMA, 2-phase double-buffered staging (round-10 proven, 43.1us) ----
// bmat bf16 [t][b][h*10+k]
__global__ __launch_bounds__(256) void gemm_b_mfma(const __hip_bfloat16* __restrict__ xb,
        const __hip_bfloat16* __restrict__ wb, const float* __restrict__ xninfo,
        __hip_bfloat16* __restrict__ bmat) {
    __shared__ __hip_bfloat16 As[2][4096];   // 2 x [128][32]
    __shared__ __hip_bfloat16 Bs[2][4096];
    int tid = threadIdx.x;
    int wid = tid >> 6, lane = tid & 63;
    int m0 = blockIdx.x * 128, n0 = blockIdx.y * 128;
    int wr = wid >> 1, wc = wid & 1;
    int srow = tid >> 2;
    int scol = (tid & 3) * 8;
    f32x4 acc[4][4] = {};

    const __hip_bfloat16* ga0 = xb + (size_t)(m0 + srow) * IN_DIM + scol;
    const __hip_bfloat16* gb0 = wb + (size_t)(n0 + srow) * IN_DIM + scol;

    #pragma unroll
    for (int half = 0; half < 2; ++half) {
        __builtin_amdgcn_global_load_lds((const GLOBAL_AS void*)(ga0 + half * 64 * IN_DIM),
            (LDS_AS void*)(&As[0][half * 2048 + wid * 512]), 16, 0, 0);
        __builtin_amdgcn_global_load_lds((const GLOBAL_AS void*)(gb0 + half * 64 * IN_DIM),
            (LDS_AS void*)(&Bs[0][half * 2048 + wid * 512]), 16, 0, 0);
    }
    __syncthreads();

    int cur = 0;
    for (int step = 0; step < 8; ++step) {
        if (step < 7) {
            int kbn = (step + 1) * 32;
            #pragma unroll
            for (int half = 0; half < 2; ++half) {
                __builtin_amdgcn_global_load_lds((const GLOBAL_AS void*)(ga0 + half * 64 * IN_DIM + kbn),
                    (LDS_AS void*)(&As[cur ^ 1][half * 2048 + wid * 512]), 16, 0, 0);
                __builtin_amdgcn_global_load_lds((const GLOBAL_AS void*)(gb0 + half * 64 * IN_DIM + kbn),
                    (LDS_AS void*)(&Bs[cur ^ 1][half * 2048 + wid * 512]), 16, 0, 0);
            }
        }
        int seg = (lane >> 4) * 8;
        int rl = lane & 15;
        short8 a[4], b[4];
        #pragma unroll
        for (int m = 0; m < 4; ++m)
            a[m] = *(const short8*)(&As[cur][(wr * 64 + m * 16 + rl) * 32 + seg]);
        #pragma unroll
        for (int n = 0; n < 4; ++n)
            b[n] = *(const short8*)(&Bs[cur][(wc * 64 + n * 16 + rl) * 32 + seg]);
        #pragma unroll
        for (int m = 0; m < 4; ++m)
            #pragma unroll
            for (int n = 0; n < 4; ++n)
                acc[m][n] = __builtin_amdgcn_mfma_f32_16x16x32_bf16(a[m], b[n], acc[m][n], 0, 0, 0);
        __syncthreads();
        cur ^= 1;
    }

    int col_l = lane & 15;
    int rseg = (lane >> 4) * 4;
    #pragma unroll
    for (int m = 0; m < 4; ++m) {
        int rbase = m0 + wr * 64 + m * 16 + rseg;
        float4 q0 = *(const float4*)(xninfo + 2 * rbase);
        float4 q1 = *(const float4*)(xninfo + 2 * rbase + 4);
        float nrm[4] = { q0.x, q0.z, q1.x, q1.z };
        float inv[4] = { q0.y, q0.w, q1.y, q1.w };
        #pragma unroll
        for (int n = 0; n < 4; ++n) {
            int col = n0 + wc * 64 + n * 16 + col_l;     // = h*10+k directly
            #pragma unroll
            for (int j = 0; j < 4; ++j) {
                float bv = nrm[j] * __expf(0.4f * acc[m][n][j] * inv[j] - 0.4f);
                bmat[(size_t)(rbase + j) * NKH + col] = __float2bfloat16(bv);
            }
        }
    }
}

// ---- Gram split-K partial, 2-phase pipeline: Mpart[kz] = wb2[:,kz*160:+160] @ wb2^T ----
__global__ __launch_bounds__(256) void gram_partial(const __hip_bfloat16* __restrict__ wb2,
        float* __restrict__ Mpart) {
    __shared__ __hip_bfloat16 As[2][4096];
    __shared__ __hip_bfloat16 Bs[2][4096];
    int tid = threadIdx.x;
    int wid = tid >> 6, lane = tid & 63;
    int m0 = blockIdx.x * 128, n0 = blockIdx.y * 128;
    int kz = blockIdx.z;
    int wr = wid >> 1, wc = wid & 1;
    int srow = tid >> 2;
    int scol = (tid & 3) * 8;
    f32x4 acc[4][4] = {};

    const __hip_bfloat16* ga0 = wb2 + (size_t)(m0 + srow) * NKH + kz * 160 + scol;
    const __hip_bfloat16* gb0 = wb2 + (size_t)(n0 + srow) * NKH + kz * 160 + scol;

    #pragma unroll
    for (int half = 0; half < 2; ++half) {
        __builtin_amdgcn_global_load_lds((const GLOBAL_AS void*)(ga0 + half * 64 * NKH),
            (LDS_AS void*)(&As[0][half * 2048 + wid * 512]), 16, 0, 0);
        __builtin_amdgcn_global_load_lds((const GLOBAL_AS void*)(gb0 + half * 64 * NKH),
            (LDS_AS void*)(&Bs[0][half * 2048 + wid * 512]), 16, 0, 0);
    }
    __syncthreads();

    int cur = 0;
    for (int ks = 0; ks < 5; ++ks) {
        if (ks < 4) {
            int kbn = (ks + 1) * 32;
            #pragma unroll
            for (int half = 0; half < 2; ++half) {
                __builtin_amdgcn_global_load_lds((const GLOBAL_AS void*)(ga0 + half * 64 * NKH + kbn),
                    (LDS_AS void*)(&As[cur ^ 1][half * 2048 + wid * 512]), 16, 0, 0);
                __builtin_amdgcn_global_load_lds((const GLOBAL_AS void*)(gb0 + half * 64 * NKH + kbn),
                    (LDS_AS void*)(&Bs[cur ^ 1][half * 2048 + wid * 512]), 16, 0, 0);
            }
        }
        int seg = (lane >> 4) * 8;
        int rl = lane & 15;
        short8 a[4], b[4];
        #pragma unroll
        for (int m = 0; m < 4; ++m)
            a[m] = *(const short8*)(&As[cur][(wr * 64 + m * 16 + rl) * 32 + seg]);
        #pragma unroll
        for (int n = 0; n < 4; ++n)
            b[n] = *(const short8*)(&Bs[cur][(wc * 64 + n * 16 + rl) * 32 + seg]);
        #pragma unroll
        for (int m = 0; m < 4; ++m)
            #pragma unroll
            for (int n = 0; n < 4; ++n)
                acc[m][n] = __builtin_amdgcn_mfma_f32_16x16x32_bf16(a[m], b[n], acc[m][n], 0, 0, 0);
        __syncthreads();
        cur ^= 1;
    }

    float* dst = Mpart + (size_t)kz * 65536;
    int col_l = lane & 15;
    int rseg = (lane >> 4) * 4;
    #pragma unroll
    for (int m = 0; m < 4; ++m) {
        int rbase = m0 + wr * 64 + m * 16 + rseg;
        #pragma unroll
        for (int n = 0; n < 4; ++n) {
            int col = n0 + wc * 64 + n * 16 + col_l;
            #pragma unroll
            for (int j = 0; j < 4; ++j)
                dst[(size_t)(rbase + j) * H_DIM + col] = acc[m][n][j];
        }
    }
}

// ---- Gram finish: Mm = exp(0.4*sum_kz Mpart - 4), rsum[row] = row sum ----
__global__ __launch_bounds__(256) void gram_finish(const float* __restrict__ Mpart,
        float* __restrict__ Mm, float* __restrict__ rsum) {
    __shared__ float red[256];
    int r = blockIdx.x, c = threadIdx.x;
    float s = 0.f;
    #pragma unroll
    for (int kz = 0; kz < 16; ++kz)
        s += Mpart[(size_t)kz * 65536 + (size_t)r * H_DIM + c];
    float e = __expf(0.4f * s - 4.0f);
    Mm[(size_t)r * H_DIM + c] = e;
    red[c] = e;
    __syncthreads();
    #pragma unroll
    for (int st = 128; st > 0; st >>= 1) {
        if (c < st) red[c] += red[c + st];
        __syncthreads();
    }
    if (c == 0) rsum[r] = red[0];
}

// ---- shared power-iteration phase: fills vv (unit Perron vector), returns lam ----
__device__ __forceinline__ float power_phase(const float* __restrict__ Mm,
        const float* __restrict__ rsum, float* vv, float* red, int tid) {
    vv[tid] = rsum[tid];
    __syncthreads();
    float lam = 0.f;
    for (int it = 0; it <= NPOW; ++it) {
        float p = 0.f;
        #pragma unroll 8
        for (int g = 0; g < 256; ++g) p = fmaf(Mm[(size_t)g * 256 + tid], vv[g], p);
        __syncthreads();
        if (it < NPOW) {
            red[tid] = p * p;
            __syncthreads();
            #pragma unroll
            for (int st = 128; st > 0; st >>= 1) {
                if (tid < st) red[tid] += red[tid + st];
                __syncthreads();
            }
            float inv = rsqrtf(red[0]);
            __syncthreads();
            vv[tid] = p * inv;
            __syncthreads();
        } else {
            red[tid] = p * vv[tid];     // Rayleigh quotient (||v||=1)
            __syncthreads();
            #pragma unroll
            for (int st = 128; st > 0; st >>= 1) {
                if (tid < st) red[tid] += red[tid + st];
                __syncthreads();
            }
            lam = red[0];
            __syncthreads();
        }
    }
    return lam;
}

// ---- P2: E2 = E @ E, 16 blocks x 64x64 tile; embedded power phase; E from Mm on the fly ----
__global__ __launch_bounds__(256) void e2_kernel(const float* __restrict__ Mm,
        const float* __restrict__ rsum, float* __restrict__ E2g,
        __hip_bfloat16* __restrict__ e2b) {
    __shared__ __hip_bfloat16 EA[16384];   // [64][256] bf16, row-swizzled
    __shared__ __hip_bfloat16 EC[16384];
    __shared__ float vv[256];
    __shared__ float redl[256];
    int tid = threadIdx.x;
    int r0 = (blockIdx.x >> 2) * 64, c0 = (blockIdx.x & 3) * 64;
    float lam = power_phase(Mm, rsum, vv, redl, tid);
    float lm1 = lam - 1.f;
    char* pa = (char*)EA;
    char* pc = (char*)EC;
    for (int f = tid; f < 4096; f += 256) {
        int row = f >> 6, c4 = (f & 63) << 2;
        {
            int r = r0 + row;
            float4 mv = *(const float4*)(Mm + (size_t)r * 256 + c4);
            float vr = lm1 * vv[r];
            __hip_bfloat16 hb[4];
            hb[0] = __float2bfloat16(mv.x - ((r == c4 + 0) ? 1.f : 0.f) - vr * vv[c4 + 0]);
            hb[1] = __float2bfloat16(mv.y - ((r == c4 + 1) ? 1.f : 0.f) - vr * vv[c4 + 1]);
            hb[2] = __float2bfloat16(mv.z - ((r == c4 + 2) ? 1.f : 0.f) - vr * vv[c4 + 2]);
            hb[3] = __float2bfloat16(mv.w - ((r == c4 + 3) ? 1.f : 0.f) - vr * vv[c4 + 3]);
            *(short4*)(pa + row * 512 + ((c4 * 2) ^ ((row & 7) << 4))) = *(short4*)hb;
        }
        {
            int r = c0 + row;
            float4 mv = *(const float4*)(Mm + (size_t)r * 256 + c4);
            float vr = lm1 * vv[r];
            __hip_bfloat16 hb[4];
            hb[0] = __float2bfloat16(mv.x - ((r == c4 + 0) ? 1.f : 0.f) - vr * vv[c4 + 0]);
            hb[1] = __float2bfloat16(mv.y - ((r == c4 + 1) ? 1.f : 0.f) - vr * vv[c4 + 1]);
            hb[2] = __float2bfloat16(mv.z - ((r == c4 + 2) ? 1.f : 0.f) - vr * vv[c4 + 2]);
            hb[3] = __float2bfloat16(mv.w - ((r == c4 + 3) ? 1.f : 0.f) - vr * vv[c4 + 3]);
            *(short4*)(pc + row * 512 + ((c4 * 2) ^ ((row & 7) << 4))) = *(short4*)hb;
        }
    }
    __syncthreads();
    int wv = tid >> 6, lane = tid & 63;
    int rl = lane & 15, seg8 = (lane >> 4) * 8;
    f32x4 acc[4] = {};
    for (int kb = 0; kb < 256; kb += 32) {
        int row = wv * 16 + rl;
        short8 a = *(const short8*)(pa + row * 512 + (((kb + seg8) * 2) ^ ((rl & 7) << 4)));
        short8 b[4];
        #pragma unroll
        for (int n = 0; n < 4; ++n) {
            int rowb = n * 16 + rl;
            b[n] = *(const short8*)(pc + rowb * 512 + (((kb + seg8) * 2) ^ ((rl & 7) << 4)));
        }
        #pragma unroll
        for (int n = 0; n < 4; ++n)
            acc[n] = __builtin_amdgcn_mfma_f32_16x16x32_bf16(a, b[n], acc[n], 0, 0, 0);
    }
    int col_l = lane & 15, rseg = (lane >> 4) * 4;
    #pragma unroll
    for (int n = 0; n < 4; ++n) {
        #pragma unroll
        for (int j = 0; j < 4; ++j) {
            int r = r0 + wv * 16 + rseg + j;
            int c = c0 + n * 16 + col_l;
            size_t idx = (size_t)r * 256 + c;
            E2g[idx] = acc[n][j];
            e2b[idx] = __float2bfloat16(acc[n][j]);
        }
    }
}

// ---- P3: E3 = E @ E2; embedded power; lin = 1.5I - Mm/2 + (lm1/2+lfac) vv^T + 3/8 E2 - 5/16 E3
__global__ __launch_bounds__(256) void e3lin_kernel(const float* __restrict__ Mm,
        const float* __restrict__ rsum, const float* __restrict__ E2g,
        const __hip_bfloat16* __restrict__ e2b,
        float* __restrict__ lin, __hip_bfloat16* __restrict__ linb) {
    __shared__ __hip_bfloat16 EA[16384];   // [64][256] E rows, swizzled
    __shared__ __hip_bfloat16 EC[16384];   // [64][256] E2 rows (symmetric), swizzled
    __shared__ float vv[256];
    __shared__ float redl[256];
    int tid = threadIdx.x;
    int r0 = (blockIdx.x >> 2) * 64, c0 = (blockIdx.x & 3) * 64;
    float lam = power_phase(Mm, rsum, vv, redl, tid);
    float lm1 = lam - 1.f;
    float wfac = 0.5f * lm1 + (rsqrtf(lam) - 1.f);
    char* pa = (char*)EA;
    char* pc = (char*)EC;
    for (int f = tid; f < 4096; f += 256) {
        int row = f >> 6, c4 = (f & 63) << 2;
        int r = r0 + row;
        float4 mv = *(const float4*)(Mm + (size_t)r * 256 + c4);
        float vr = lm1 * vv[r];
        __hip_bfloat16 hb[4];
        hb[0] = __float2bfloat16(mv.x - ((r == c4 + 0) ? 1.f : 0.f) - vr * vv[c4 + 0]);
        hb[1] = __float2bfloat16(mv.y - ((r == c4 + 1) ? 1.f : 0.f) - vr * vv[c4 + 1]);
        hb[2] = __float2bfloat16(mv.z - ((r == c4 + 2) ? 1.f : 0.f) - vr * vv[c4 + 2]);
        hb[3] = __float2bfloat16(mv.w - ((r == c4 + 3) ? 1.f : 0.f) - vr * vv[c4 + 3]);
        *(short4*)(pa + row * 512 + ((c4 * 2) ^ ((row & 7) << 4))) = *(short4*)hb;
    }
    for (int f = tid; f < 2048; f += 256) {
        int row = f >> 5, c8 = (f & 31) << 3;
        short8 v8 = *(const short8*)(e2b + (size_t)(c0 + row) * 256 + c8);
        *(short8*)(pc + row * 512 + ((c8 * 2) ^ ((row & 7) << 4))) = v8;
    }
    __syncthreads();
    int wv = tid >> 6, lane = tid & 63;
    int rl = lane & 15, seg8 = (lane >> 4) * 8;
    f32x4 acc[4] = {};
    for (int kb = 0; kb < 256; kb += 32) {
        int row = wv * 16 + rl;
        short8 a = *(const short8*)(pa + row * 512 + (((kb + seg8) * 2) ^ ((rl & 7) << 4)));
        short8 b[4];
        #pragma unroll
        for (int n = 0; n < 4; ++n) {
            int rowb = n * 16 + rl;
            b[n] = *(const short8*)(pc + rowb * 512 + (((kb + seg8) * 2) ^ ((rl & 7) << 4)));
        }
        #pragma unroll
        for (int n = 0; n < 4; ++n)
            acc[n] = __builtin_amdgcn_mfma_f32_16x16x32_bf16(a, b[n], acc[n], 0, 0, 0);
    }
    int col_l = lane & 15, rseg = (lane >> 4) * 4;
    #pragma unroll
    for (int n = 0; n < 4; ++n) {
        #pragma unroll
        for (int j = 0; j < 4; ++j) {
            int r = r0 + wv * 16 + rseg + j;
            int c = c0 + n * 16 + col_l;
            size_t idx = (size_t)r * 256 + c;
            float lv = ((r == c) ? 1.5f : 0.f) - 0.5f * Mm[idx] + wfac * vv[r] * vv[c]
                     + 0.375f * E2g[idx] - 0.3125f * acc[n][j];
            lin[idx] = lv;
            linb[idx] = __float2bfloat16(lv);
        }
    }
}

// ---- megarec2: 256 blocks x 512 threads; block = (s 0..7, b). Sub-group pairing:
// sub=tid>>8; outputs [s*64+sub*32, +32), warm-up 32 (sub1's warm range = sub0's output
// range -> L2 re-read; unique HBM = 96 rows/64 outputs = 1.5x). Then fused out1 GEMM. ----
__global__ __launch_bounds__(512) void megarec2(const __hip_bfloat16* __restrict__ bmat,
        const __hip_bfloat16* __restrict__ linb, float* __restrict__ out1,
        float* __restrict__ part, float* __restrict__ hxT) {
    __shared__ __hip_bfloat16 c9t[16384];  // [64][256] bf16, row-swizzled (32 KB)
    int tid = threadIdx.x;
    int sub = tid >> 8;                    // 0 or 1
    int h = tid & 255;
    int s = blockIdx.x >> 5;               // 0..7
    int b = blockIdx.x & 31;
    int tout0 = s * 64;
    int start = tout0 + sub * 32;
    int t0 = (start == 0) ? 0 : start - 32;
    int t1 = start + 32;
    char* c9p = (char*)c9t;
    float c[10] = {};
    float s9 = 0.f;
    int4u v0; int v1;
    {
        const char* bp = (const char*)bmat + ((size_t)(t0 * B_DIM + b) * NKH + h * 10) * 2;
        v0 = *(const int4u*)bp;
        v1 = *(const int*)(bp + 16);
    }
    for (int t = t0; t < t1; ++t) {
        int tn = (t + 1 < t1) ? t + 1 : t;
        const char* bq = (const char*)bmat + ((size_t)(tn * B_DIM + b) * NKH + h * 10) * 2;
        int4u w0 = *(const int4u*)bq;
        int w1 = *(const int*)(bq + 16);
        float bt[10];
        bt[0] = bf_lo(v0.x); bt[1] = bf_hi(v0.x);
        bt[2] = bf_lo(v0.y); bt[3] = bf_hi(v0.y);
        bt[4] = bf_lo(v0.z); bt[5] = bf_hi(v0.z);
        bt[6] = bf_lo(v0.w); bt[7] = bf_hi(v0.w);
        bt[8] = bf_lo(v1);   bt[9] = bf_hi(v1);
        #pragma unroll
        for (int j = 9; j >= 1; --j) c[j] = 0.5f * c[j] + c[j - 1] * bt[j];
        c[0] = 0.5f * c[0] + bt[0];
        if (t >= start) {
            int tt = t - tout0;            // sub0: 0..31, sub1: 32..63
            *(__hip_bfloat16*)(c9p + tt * 512 + ((h * 2) ^ ((tt & 7) << 4))) = __float2bfloat16(c[9]);
            s9 += c[9];
        }
        v0 = w0; v1 = w1;
    }
    part[(size_t)((s * 2 + sub) * B_DIM + b) * H_DIM + h] = s9;
    if (s == 7 && sub == 1) {
        float* hp = hxT + (size_t)(b * H_DIM + h) * K_DIM;
        #pragma unroll
        for (int k = 0; k < 10; ++k) hp[k] = c[k];
    }
    __syncthreads();
    // out1 GEMM: [64 tt] x [256 h] @ linb -> out1[tout0+tt][b][g]; 8 waves, wave wid owns
    // g in [wid*32, +32) (2 n-frags), 4 m-frags over tt.
    int wid = tid >> 6, lane = tid & 63;
    int rl = lane & 15, seg8 = (lane >> 4) * 8;
    int col_l = lane & 15, rseg = (lane >> 4) * 4;
    f32x4 acc[4][2] = {};
    for (int kb = 0; kb < 256; kb += 32) {
        short8 a[4];
        #pragma unroll
        for (int m = 0; m < 4; ++m) {
            int row = m * 16 + rl;
            a[m] = *(const short8*)(c9p + row * 512 + (((kb + seg8) * 2) ^ ((row & 7) << 4)));
        }
        short8 bf[2];
        #pragma unroll
        for (int n = 0; n < 2; ++n)
            bf[n] = *(const short8*)(linb + (size_t)(wid * 32 + n * 16 + rl) * 256 + kb + seg8);
        #pragma unroll
        for (int m = 0; m < 4; ++m)
            #pragma unroll
            for (int n = 0; n < 2; ++n)
                acc[m][n] = __builtin_amdgcn_mfma_f32_16x16x32_bf16(a[m], bf[n], acc[m][n], 0, 0, 0);
    }
    #pragma unroll
    for (int m = 0; m < 4; ++m) {
        #pragma unroll
        for (int n = 0; n < 2; ++n) {
            int g = wid * 32 + n * 16 + col_l;
            #pragma unroll
            for (int j = 0; j < 4; ++j) {
                int tt = m * 16 + rseg + j;
                out1[((size_t)(tout0 + tt) * B_DIM + b) * H_DIM + g] = acc[m][n][j];
            }
        }
    }
}

// ---- recout: mean over T of c9 (from part) then out0 = mean @ lin, one block per b ----
__global__ __launch_bounds__(256) void recout_kernel(const float* __restrict__ part,
        const float* __restrict__ lin, float* __restrict__ out0) {
    __shared__ float mrow[256];
    int b = blockIdx.x, tid = threadIdx.x;
    float s = 0.f;
    #pragma unroll
    for (int j = 0; j < 16; ++j) s += part[(size_t)(j * B_DIM + b) * H_DIM + tid];
    mrow[tid] = s * (1.f / T_DIM);
    __syncthreads();
    float acc = 0.f;
    #pragma unroll 8
    for (int h = 0; h < H_DIM; ++h) acc = fmaf(mrow[h], lin[(size_t)h * H_DIM + tid], acc);
    out0[b * H_DIM + tid] = acc;
}

extern "C" void kernel_launch(void* const* d_in, const int* in_sizes, int n_in,
                              void* d_out, int out_size, void* d_ws, size_t ws_size,
                              hipStream_t stream) {
    const float* x = (const float*)d_in[0];
    const float* w = (const float*)d_in[1];
    float* out0 = (float*)d_out;                       // B*H
    float* out1 = out0 + (size_t)B_DIM * H_DIM;        // T*B*H
    float* hxT  = out1 + (size_t)TB * H_DIM;           // B*H*K

    char* ws = (char*)d_ws;
    __hip_bfloat16* wb   = (__hip_bfloat16*)(ws + 0);          // 1,310,720
    __hip_bfloat16* wb2  = (__hip_bfloat16*)(ws + 1310720);    // 1,310,720
    float* xninfo        = (float*)(ws + 2621440);             //   131,072
    float* Mm            = (float*)(ws + 2752512);             //   262,144
    float* rsum          = (float*)(ws + 3014656);             //     1,024
    float* E2g           = (float*)(ws + 3015680);             //   262,144
    __hip_bfloat16* e2b  = (__hip_bfloat16*)(ws + 3277824);    //   131,072
    float* lin           = (float*)(ws + 3408896);             //   262,144
    __hip_bfloat16* linb = (__hip_bfloat16*)(ws + 3671040);    //   131,072
    float* part          = (float*)(ws + 3802112);             //   524,288 (16 slots)
    float* Mpart         = (float*)(ws + 4326400);             // 4,194,304
    __hip_bfloat16* xb   = (__hip_bfloat16*)(ws + 8520704);    // 8,388,608
    __hip_bfloat16* bmat = (__hip_bfloat16*)(ws + 16909312);   // 83,886,080 -> ~100.8 MB

    prep_kernel<<<dim3(4736), dim3(256), 0, stream>>>(w, x, wb, wb2, xninfo, xb);
    gemm_b_mfma<<<dim3(128, 20), dim3(256), 0, stream>>>(xb, wb, xninfo, bmat);
    gram_partial<<<dim3(2, 2, 16), dim3(256), 0, stream>>>(wb2, Mpart);
    gram_finish<<<dim3(256), dim3(256), 0, stream>>>(Mpart, Mm, rsum);
    e2_kernel<<<dim3(16), dim3(256), 0, stream>>>(Mm, rsum, E2g, e2b);
    e3lin_kernel<<<dim3(16), dim3(256), 0, stream>>>(Mm, rsum, E2g, e2b, lin, linb);
    megarec2<<<dim3(256), dim3(512), 0, stream>>>(bmat, linb, out1, part, hxT);
    recout_kernel<<<dim3(32), dim3(256), 0, stream>>>(part, lin, out0);
}

// Round 15
// 135.263 us; speedup vs baseline: 1.2480x; 1.1783x over previous
//
#include <hip/hip_runtime.h>
#include <hip/hip_bf16.h>

// Problem dims
#define T_DIM 512
#define B_DIM 32
#define IN_DIM 256
#define H_DIM 256
#define K_DIM 10
#define TB 16384          // T*B
#define NKH 2560          // H*K
#define NPOW 3            // normalized power updates (v0 = rsum = M@1 is already 1 step)

typedef __attribute__((ext_vector_type(8))) short short8;
typedef __attribute__((ext_vector_type(4))) float f32x4;
typedef __attribute__((ext_vector_type(4), aligned(4))) int int4u;   // 4B-aligned dwordx4

#define GLOBAL_AS __attribute__((address_space(1)))
#define LDS_AS __attribute__((address_space(3)))

__device__ __forceinline__ float wave_sum64(float v) {
    #pragma unroll
    for (int off = 32; off > 0; off >>= 1) v += __shfl_xor(v, off, 64);
    return v;
}

__device__ __forceinline__ float bf_lo(int u) { return __int_as_float(u << 16); }
__device__ __forceinline__ float bf_hi(int u) { return __int_as_float(u & 0xffff0000); }

// ---- prep: weight normalize (blocks 0..639) + x norms/bf16 (blocks 640..4735) ----
__global__ __launch_bounds__(256) void prep_kernel(const float* __restrict__ w,
        const float* __restrict__ x, __hip_bfloat16* __restrict__ wb,
        __hip_bfloat16* __restrict__ wb2, float* __restrict__ xninfo,
        __hip_bfloat16* __restrict__ xb) {
    int wv = threadIdx.x >> 6, lane = threadIdx.x & 63;
    if (blockIdx.x < 640) {
        int row = blockIdx.x * 4 + wv;                 // 0..2559  (= h*10+k)
        const float* src = w + (size_t)row * IN_DIM;
        float v[4]; float s = 0.f;
        #pragma unroll
        for (int j = 0; j < 4; ++j) { v[j] = src[lane + 64 * j]; s += v[j] * v[j]; }
        s = wave_sum64(s);
        float inv = 1.f / fmaxf(sqrtf(s), 1e-4f);
        int h = row / K_DIM, k = row % K_DIM;
        __hip_bfloat16* d1 = wb + (size_t)row * IN_DIM;
        __hip_bfloat16* d2 = wb2 + (size_t)h * NKH + k * IN_DIM;
        #pragma unroll
        for (int j = 0; j < 4; ++j) {
            __hip_bfloat16 t = __float2bfloat16(v[j] * inv);
            d1[lane + 64 * j] = t;
            d2[lane + 64 * j] = t;
        }
    } else {
        int row = (blockIdx.x - 640) * 4 + wv;         // 0..16383
        const float* src = x + (size_t)row * IN_DIM;
        float v[4]; float s = 0.f;
        #pragma unroll
        for (int j = 0; j < 4; ++j) { v[j] = src[lane + 64 * j]; s += v[j] * v[j]; }
        s = wave_sum64(s);
        float nrm = sqrtf(s);
        if (lane == 0) { xninfo[2 * row] = nrm; xninfo[2 * row + 1] = 1.f / fmaxf(nrm, 1e-4f); }
        __hip_bfloat16* d = xb + (size_t)row * IN_DIM;
        #pragma unroll
        for (int j = 0; j < 4; ++j) d[lane + 64 * j] = __float2bfloat16(v[j]);
    }
}

// ---- big GEMM via bf16 MFMA, 2-phase double-buffered staging (proven 43.0us) ----
// bmat bf16 [t][b][h*10+k]
__global__ __launch_bounds__(256) void gemm_b_mfma(const __hip_bfloat16* __restrict__ xb,
        const __hip_bfloat16* __restrict__ wb, const float* __restrict__ xninfo,
        __hip_bfloat16* __restrict__ bmat) {
    __shared__ __hip_bfloat16 As[2][4096];   // 2 x [128][32]
    __shared__ __hip_bfloat16 Bs[2][4096];
    int tid = threadIdx.x;
    int wid = tid >> 6, lane = tid & 63;
    int m0 = blockIdx.x * 128, n0 = blockIdx.y * 128;
    int wr = wid >> 1, wc = wid & 1;
    int srow = tid >> 2;
    int scol = (tid & 3) * 8;
    f32x4 acc[4][4] = {};

    const __hip_bfloat16* ga0 = xb + (size_t)(m0 + srow) * IN_DIM + scol;
    const __hip_bfloat16* gb0 = wb + (size_t)(n0 + srow) * IN_DIM + scol;

    #pragma unroll
    for (int half = 0; half < 2; ++half) {
        __builtin_amdgcn_global_load_lds((const GLOBAL_AS void*)(ga0 + half * 64 * IN_DIM),
            (LDS_AS void*)(&As[0][half * 2048 + wid * 512]), 16, 0, 0);
        __builtin_amdgcn_global_load_lds((const GLOBAL_AS void*)(gb0 + half * 64 * IN_DIM),
            (LDS_AS void*)(&Bs[0][half * 2048 + wid * 512]), 16, 0, 0);
    }
    __syncthreads();

    int cur = 0;
    for (int step = 0; step < 8; ++step) {
        if (step < 7) {
            int kbn = (step + 1) * 32;
            #pragma unroll
            for (int half = 0; half < 2; ++half) {
                __builtin_amdgcn_global_load_lds((const GLOBAL_AS void*)(ga0 + half * 64 * IN_DIM + kbn),
                    (LDS_AS void*)(&As[cur ^ 1][half * 2048 + wid * 512]), 16, 0, 0);
                __builtin_amdgcn_global_load_lds((const GLOBAL_AS void*)(gb0 + half * 64 * IN_DIM + kbn),
                    (LDS_AS void*)(&Bs[cur ^ 1][half * 2048 + wid * 512]), 16, 0, 0);
            }
        }
        int seg = (lane >> 4) * 8;
        int rl = lane & 15;
        short8 a[4], b[4];
        #pragma unroll
        for (int m = 0; m < 4; ++m)
            a[m] = *(const short8*)(&As[cur][(wr * 64 + m * 16 + rl) * 32 + seg]);
        #pragma unroll
        for (int n = 0; n < 4; ++n)
            b[n] = *(const short8*)(&Bs[cur][(wc * 64 + n * 16 + rl) * 32 + seg]);
        #pragma unroll
        for (int m = 0; m < 4; ++m)
            #pragma unroll
            for (int n = 0; n < 4; ++n)
                acc[m][n] = __builtin_amdgcn_mfma_f32_16x16x32_bf16(a[m], b[n], acc[m][n], 0, 0, 0);
        __syncthreads();
        cur ^= 1;
    }

    int col_l = lane & 15;
    int rseg = (lane >> 4) * 4;
    #pragma unroll
    for (int m = 0; m < 4; ++m) {
        int rbase = m0 + wr * 64 + m * 16 + rseg;
        float4 q0 = *(const float4*)(xninfo + 2 * rbase);
        float4 q1 = *(const float4*)(xninfo + 2 * rbase + 4);
        float nrm[4] = { q0.x, q0.z, q1.x, q1.z };
        float inv[4] = { q0.y, q0.w, q1.y, q1.w };
        #pragma unroll
        for (int n = 0; n < 4; ++n) {
            int col = n0 + wc * 64 + n * 16 + col_l;     // = h*10+k directly
            #pragma unroll
            for (int j = 0; j < 4; ++j) {
                float bv = nrm[j] * __expf(0.4f * acc[m][n][j] * inv[j] - 0.4f);
                bmat[(size_t)(rbase + j) * NKH + col] = __float2bfloat16(bv);
            }
        }
    }
}

// ---- Gram split-K partial, 2-phase pipeline: Mpart[kz] = wb2[:,kz*160:+160] @ wb2^T ----
__global__ __launch_bounds__(256) void gram_partial(const __hip_bfloat16* __restrict__ wb2,
        float* __restrict__ Mpart) {
    __shared__ __hip_bfloat16 As[2][4096];
    __shared__ __hip_bfloat16 Bs[2][4096];
    int tid = threadIdx.x;
    int wid = tid >> 6, lane = tid & 63;
    int m0 = blockIdx.x * 128, n0 = blockIdx.y * 128;
    int kz = blockIdx.z;
    int wr = wid >> 1, wc = wid & 1;
    int srow = tid >> 2;
    int scol = (tid & 3) * 8;
    f32x4 acc[4][4] = {};

    const __hip_bfloat16* ga0 = wb2 + (size_t)(m0 + srow) * NKH + kz * 160 + scol;
    const __hip_bfloat16* gb0 = wb2 + (size_t)(n0 + srow) * NKH + kz * 160 + scol;

    #pragma unroll
    for (int half = 0; half < 2; ++half) {
        __builtin_amdgcn_global_load_lds((const GLOBAL_AS void*)(ga0 + half * 64 * NKH),
            (LDS_AS void*)(&As[0][half * 2048 + wid * 512]), 16, 0, 0);
        __builtin_amdgcn_global_load_lds((const GLOBAL_AS void*)(gb0 + half * 64 * NKH),
            (LDS_AS void*)(&Bs[0][half * 2048 + wid * 512]), 16, 0, 0);
    }
    __syncthreads();

    int cur = 0;
    for (int ks = 0; ks < 5; ++ks) {
        if (ks < 4) {
            int kbn = (ks + 1) * 32;
            #pragma unroll
            for (int half = 0; half < 2; ++half) {
                __builtin_amdgcn_global_load_lds((const GLOBAL_AS void*)(ga0 + half * 64 * NKH + kbn),
                    (LDS_AS void*)(&As[cur ^ 1][half * 2048 + wid * 512]), 16, 0, 0);
                __builtin_amdgcn_global_load_lds((const GLOBAL_AS void*)(gb0 + half * 64 * NKH + kbn),
                    (LDS_AS void*)(&Bs[cur ^ 1][half * 2048 + wid * 512]), 16, 0, 0);
            }
        }
        int seg = (lane >> 4) * 8;
        int rl = lane & 15;
        short8 a[4], b[4];
        #pragma unroll
        for (int m = 0; m < 4; ++m)
            a[m] = *(const short8*)(&As[cur][(wr * 64 + m * 16 + rl) * 32 + seg]);
        #pragma unroll
        for (int n = 0; n < 4; ++n)
            b[n] = *(const short8*)(&Bs[cur][(wc * 64 + n * 16 + rl) * 32 + seg]);
        #pragma unroll
        for (int m = 0; m < 4; ++m)
            #pragma unroll
            for (int n = 0; n < 4; ++n)
                acc[m][n] = __builtin_amdgcn_mfma_f32_16x16x32_bf16(a[m], b[n], acc[m][n], 0, 0, 0);
        __syncthreads();
        cur ^= 1;
    }

    float* dst = Mpart + (size_t)kz * 65536;
    int col_l = lane & 15;
    int rseg = (lane >> 4) * 4;
    #pragma unroll
    for (int m = 0; m < 4; ++m) {
        int rbase = m0 + wr * 64 + m * 16 + rseg;
        #pragma unroll
        for (int n = 0; n < 4; ++n) {
            int col = n0 + wc * 64 + n * 16 + col_l;
            #pragma unroll
            for (int j = 0; j < 4; ++j)
                dst[(size_t)(rbase + j) * H_DIM + col] = acc[m][n][j];
        }
    }
}

// ---- Gram finish: Mm = exp(0.4*sum_kz Mpart - 4), rsum[row] = row sum ----
__global__ __launch_bounds__(256) void gram_finish(const float* __restrict__ Mpart,
        float* __restrict__ Mm, float* __restrict__ rsum) {
    __shared__ float red[256];
    int r = blockIdx.x, c = threadIdx.x;
    float s = 0.f;
    #pragma unroll
    for (int kz = 0; kz < 16; ++kz)
        s += Mpart[(size_t)kz * 65536 + (size_t)r * H_DIM + c];
    float e = __expf(0.4f * s - 4.0f);
    Mm[(size_t)r * H_DIM + c] = e;
    red[c] = e;
    __syncthreads();
    #pragma unroll
    for (int st = 128; st > 0; st >>= 1) {
        if (c < st) red[c] += red[c + st];
        __syncthreads();
    }
    if (c == 0) rsum[r] = red[0];
}

// ---- standalone power iteration (1 block x 512 thr, row-split): vbuf, cbuf={lam,lam-1,rsqrt-1}
__global__ __launch_bounds__(512) void power_kernel(const float* __restrict__ Mm,
        const float* __restrict__ rsum, float* __restrict__ vbuf, float* __restrict__ cbuf) {
    __shared__ float vv[256];
    __shared__ float yv[256];
    __shared__ float red[512];
    int tid = threadIdx.x;
    if (tid < 256) vv[tid] = rsum[tid];
    __syncthreads();
    for (int it = 0; it <= NPOW; ++it) {
        int col = tid & 255, q = tid >> 8;             // q in {0,1}: 128-row chunks
        const float* mp = Mm + (size_t)q * 128 * 256 + col;
        float p = 0.f;
        #pragma unroll 8
        for (int g = 0; g < 128; ++g) p = fmaf(mp[(size_t)g * 256], vv[q * 128 + g], p);
        red[tid] = p;
        __syncthreads();
        if (it < NPOW) {
            if (tid < 256) {
                float y = red[tid] + red[tid + 256];
                yv[tid] = y;
                red[tid] = y * y;
            }
            __syncthreads();
            #pragma unroll
            for (int st = 128; st > 0; st >>= 1) {
                if (tid < st) red[tid] += red[tid + st];
                __syncthreads();
            }
            float inv = rsqrtf(red[0]);
            if (tid < 256) vv[tid] = yv[tid] * inv;
            __syncthreads();
        } else {
            if (tid < 256) red[tid] = (red[tid] + red[tid + 256]) * vv[tid];  // Rayleigh
            __syncthreads();
            #pragma unroll
            for (int st = 128; st > 0; st >>= 1) {
                if (tid < st) red[tid] += red[tid + st];
                __syncthreads();
            }
            if (tid == 0) {
                float lam = red[0];
                cbuf[0] = lam;
                cbuf[1] = lam - 1.f;
                cbuf[2] = rsqrtf(lam) - 1.f;
            }
        }
    }
    if (tid < 256) vbuf[tid] = vv[tid];
}

// ---- P2: E2 = E @ E, 16 blocks x 64x64 tile; E from Mm + vbuf on the fly ----
__global__ __launch_bounds__(256) void e2_kernel(const float* __restrict__ Mm,
        const float* __restrict__ vbuf, const float* __restrict__ cbuf,
        float* __restrict__ E2g, __hip_bfloat16* __restrict__ e2b) {
    __shared__ __hip_bfloat16 EA[16384];   // [64][256] bf16, row-swizzled
    __shared__ __hip_bfloat16 EC[16384];
    __shared__ float vv[256];
    int tid = threadIdx.x;
    int r0 = (blockIdx.x >> 2) * 64, c0 = (blockIdx.x & 3) * 64;
    float lm1 = cbuf[1];
    if (tid < 256) vv[tid] = vbuf[tid];
    __syncthreads();
    char* pa = (char*)EA;
    char* pc = (char*)EC;
    for (int f = tid; f < 4096; f += 256) {
        int row = f >> 6, c4 = (f & 63) << 2;
        {
            int r = r0 + row;
            float4 mv = *(const float4*)(Mm + (size_t)r * 256 + c4);
            float vr = lm1 * vv[r];
            __hip_bfloat16 hb[4];
            hb[0] = __float2bfloat16(mv.x - ((r == c4 + 0) ? 1.f : 0.f) - vr * vv[c4 + 0]);
            hb[1] = __float2bfloat16(mv.y - ((r == c4 + 1) ? 1.f : 0.f) - vr * vv[c4 + 1]);
            hb[2] = __float2bfloat16(mv.z - ((r == c4 + 2) ? 1.f : 0.f) - vr * vv[c4 + 2]);
            hb[3] = __float2bfloat16(mv.w - ((r == c4 + 3) ? 1.f : 0.f) - vr * vv[c4 + 3]);
            *(short4*)(pa + row * 512 + ((c4 * 2) ^ ((row & 7) << 4))) = *(short4*)hb;
        }
        {
            int r = c0 + row;
            float4 mv = *(const float4*)(Mm + (size_t)r * 256 + c4);
            float vr = lm1 * vv[r];
            __hip_bfloat16 hb[4];
            hb[0] = __float2bfloat16(mv.x - ((r == c4 + 0) ? 1.f : 0.f) - vr * vv[c4 + 0]);
            hb[1] = __float2bfloat16(mv.y - ((r == c4 + 1) ? 1.f : 0.f) - vr * vv[c4 + 1]);
            hb[2] = __float2bfloat16(mv.z - ((r == c4 + 2) ? 1.f : 0.f) - vr * vv[c4 + 2]);
            hb[3] = __float2bfloat16(mv.w - ((r == c4 + 3) ? 1.f : 0.f) - vr * vv[c4 + 3]);
            *(short4*)(pc + row * 512 + ((c4 * 2) ^ ((row & 7) << 4))) = *(short4*)hb;
        }
    }
    __syncthreads();
    int wv = tid >> 6, lane = tid & 63;
    int rl = lane & 15, seg8 = (lane >> 4) * 8;
    f32x4 acc[4] = {};
    for (int kb = 0; kb < 256; kb += 32) {
        int row = wv * 16 + rl;
        short8 a = *(const short8*)(pa + row * 512 + (((kb + seg8) * 2) ^ ((rl & 7) << 4)));
        short8 b[4];
        #pragma unroll
        for (int n = 0; n < 4; ++n) {
            int rowb = n * 16 + rl;
            b[n] = *(const short8*)(pc + rowb * 512 + (((kb + seg8) * 2) ^ ((rl & 7) << 4)));
        }
        #pragma unroll
        for (int n = 0; n < 4; ++n)
            acc[n] = __builtin_amdgcn_mfma_f32_16x16x32_bf16(a, b[n], acc[n], 0, 0, 0);
    }
    int col_l = lane & 15, rseg = (lane >> 4) * 4;
    #pragma unroll
    for (int n = 0; n < 4; ++n) {
        #pragma unroll
        for (int j = 0; j < 4; ++j) {
            int r = r0 + wv * 16 + rseg + j;
            int c = c0 + n * 16 + col_l;
            size_t idx = (size_t)r * 256 + c;
            E2g[idx] = acc[n][j];
            e2b[idx] = __float2bfloat16(acc[n][j]);
        }
    }
}

// ---- P3: E3 = E @ E2; lin = 1.5I - Mm/2 + (lm1/2+lfac) vv^T + 3/8 E2 - 5/16 E3 ----
__global__ __launch_bounds__(256) void e3lin_kernel(const float* __restrict__ Mm,
        const float* __restrict__ vbuf, const float* __restrict__ cbuf,
        const float* __restrict__ E2g, const __hip_bfloat16* __restrict__ e2b,
        float* __restrict__ lin, __hip_bfloat16* __restrict__ linb) {
    __shared__ __hip_bfloat16 EA[16384];   // [64][256] E rows, swizzled
    __shared__ __hip_bfloat16 EC[16384];   // [64][256] E2 rows (symmetric), swizzled
    __shared__ float vv[256];
    int tid = threadIdx.x;
    int r0 = (blockIdx.x >> 2) * 64, c0 = (blockIdx.x & 3) * 64;
    float lm1 = cbuf[1];
    float wfac = 0.5f * cbuf[1] + cbuf[2];
    if (tid < 256) vv[tid] = vbuf[tid];
    __syncthreads();
    char* pa = (char*)EA;
    char* pc = (char*)EC;
    for (int f = tid; f < 4096; f += 256) {
        int row = f >> 6, c4 = (f & 63) << 2;
        int r = r0 + row;
        float4 mv = *(const float4*)(Mm + (size_t)r * 256 + c4);
        float vr = lm1 * vv[r];
        __hip_bfloat16 hb[4];
        hb[0] = __float2bfloat16(mv.x - ((r == c4 + 0) ? 1.f : 0.f) - vr * vv[c4 + 0]);
        hb[1] = __float2bfloat16(mv.y - ((r == c4 + 1) ? 1.f : 0.f) - vr * vv[c4 + 1]);
        hb[2] = __float2bfloat16(mv.z - ((r == c4 + 2) ? 1.f : 0.f) - vr * vv[c4 + 2]);
        hb[3] = __float2bfloat16(mv.w - ((r == c4 + 3) ? 1.f : 0.f) - vr * vv[c4 + 3]);
        *(short4*)(pa + row * 512 + ((c4 * 2) ^ ((row & 7) << 4))) = *(short4*)hb;
    }
    for (int f = tid; f < 2048; f += 256) {
        int row = f >> 5, c8 = (f & 31) << 3;
        short8 v8 = *(const short8*)(e2b + (size_t)(c0 + row) * 256 + c8);
        *(short8*)(pc + row * 512 + ((c8 * 2) ^ ((row & 7) << 4))) = v8;
    }
    __syncthreads();
    int wv = tid >> 6, lane = tid & 63;
    int rl = lane & 15, seg8 = (lane >> 4) * 8;
    f32x4 acc[4] = {};
    for (int kb = 0; kb < 256; kb += 32) {
        int row = wv * 16 + rl;
        short8 a = *(const short8*)(pa + row * 512 + (((kb + seg8) * 2) ^ ((rl & 7) << 4)));
        short8 b[4];
        #pragma unroll
        for (int n = 0; n < 4; ++n) {
            int rowb = n * 16 + rl;
            b[n] = *(const short8*)(pc + rowb * 512 + (((kb + seg8) * 2) ^ ((rl & 7) << 4)));
        }
        #pragma unroll
        for (int n = 0; n < 4; ++n)
            acc[n] = __builtin_amdgcn_mfma_f32_16x16x32_bf16(a, b[n], acc[n], 0, 0, 0);
    }
    int col_l = lane & 15, rseg = (lane >> 4) * 4;
    #pragma unroll
    for (int n = 0; n < 4; ++n) {
        #pragma unroll
        for (int j = 0; j < 4; ++j) {
            int r = r0 + wv * 16 + rseg + j;
            int c = c0 + n * 16 + col_l;
            size_t idx = (size_t)r * 256 + c;
            float lv = ((r == c) ? 1.5f : 0.f) - 0.5f * Mm[idx] + wfac * vv[r] * vv[c]
                     + 0.375f * E2g[idx] - 0.3125f * acc[n][j];
            lin[idx] = lv;
            linb[idx] = __float2bfloat16(lv);
        }
    }
}

// ---- megarec2: 256 blocks x 512 threads; shared-warm-up pairing (1.5x unique HBM) ----
__global__ __launch_bounds__(512) void megarec2(const __hip_bfloat16* __restrict__ bmat,
        const __hip_bfloat16* __restrict__ linb, float* __restrict__ out1,
        float* __restrict__ part, float* __restrict__ hxT) {
    __shared__ __hip_bfloat16 c9t[16384];  // [64][256] bf16, row-swizzled (32 KB)
    int tid = threadIdx.x;
    int sub = tid >> 8;                    // 0 or 1
    int h = tid & 255;
    int s = blockIdx.x >> 5;               // 0..7
    int b = blockIdx.x & 31;
    int tout0 = s * 64;
    int start = tout0 + sub * 32;
    int t0 = (start == 0) ? 0 : start - 32;
    int t1 = start + 32;
    char* c9p = (char*)c9t;
    float c[10] = {};
    float s9 = 0.f;
    int4u v0; int v1;
    {
        const char* bp = (const char*)bmat + ((size_t)(t0 * B_DIM + b) * NKH + h * 10) * 2;
        v0 = *(const int4u*)bp;
        v1 = *(const int*)(bp + 16);
    }
    for (int t = t0; t < t1; ++t) {
        int tn = (t + 1 < t1) ? t + 1 : t;
        const char* bq = (const char*)bmat + ((size_t)(tn * B_DIM + b) * NKH + h * 10) * 2;
        int4u w0 = *(const int4u*)bq;
        int w1 = *(const int*)(bq + 16);
        float bt[10];
        bt[0] = bf_lo(v0.x); bt[1] = bf_hi(v0.x);
        bt[2] = bf_lo(v0.y); bt[3] = bf_hi(v0.y);
        bt[4] = bf_lo(v0.z); bt[5] = bf_hi(v0.z);
        bt[6] = bf_lo(v0.w); bt[7] = bf_hi(v0.w);
        bt[8] = bf_lo(v1);   bt[9] = bf_hi(v1);
        #pragma unroll
        for (int j = 9; j >= 1; --j) c[j] = 0.5f * c[j] + c[j - 1] * bt[j];
        c[0] = 0.5f * c[0] + bt[0];
        if (t >= start) {
            int tt = t - tout0;            // sub0: 0..31, sub1: 32..63
            *(__hip_bfloat16*)(c9p + tt * 512 + ((h * 2) ^ ((tt & 7) << 4))) = __float2bfloat16(c[9]);
            s9 += c[9];
        }
        v0 = w0; v1 = w1;
    }
    part[(size_t)((s * 2 + sub) * B_DIM + b) * H_DIM + h] = s9;
    if (s == 7 && sub == 1) {
        float* hp = hxT + (size_t)(b * H_DIM + h) * K_DIM;
        #pragma unroll
        for (int k = 0; k < 10; ++k) hp[k] = c[k];
    }
    __syncthreads();
    int wid = tid >> 6, lane = tid & 63;
    int rl = lane & 15, seg8 = (lane >> 4) * 8;
    int col_l = lane & 15, rseg = (lane >> 4) * 4;
    f32x4 acc[4][2] = {};
    for (int kb = 0; kb < 256; kb += 32) {
        short8 a[4];
        #pragma unroll
        for (int m = 0; m < 4; ++m) {
            int row = m * 16 + rl;
            a[m] = *(const short8*)(c9p + row * 512 + (((kb + seg8) * 2) ^ ((row & 7) << 4)));
        }
        short8 bf[2];
        #pragma unroll
        for (int n = 0; n < 2; ++n)
            bf[n] = *(const short8*)(linb + (size_t)(wid * 32 + n * 16 + rl) * 256 + kb + seg8);
        #pragma unroll
        for (int m = 0; m < 4; ++m)
            #pragma unroll
            for (int n = 0; n < 2; ++n)
                acc[m][n] = __builtin_amdgcn_mfma_f32_16x16x32_bf16(a[m], bf[n], acc[m][n], 0, 0, 0);
    }
    #pragma unroll
    for (int m = 0; m < 4; ++m) {
        #pragma unroll
        for (int n = 0; n < 2; ++n) {
            int g = wid * 32 + n * 16 + col_l;
            #pragma unroll
            for (int j = 0; j < 4; ++j) {
                int tt = m * 16 + rseg + j;
                out1[((size_t)(tout0 + tt) * B_DIM + b) * H_DIM + g] = acc[m][n][j];
            }
        }
    }
}

// ---- recout: mean over T of c9 (from part) then out0 = mean @ lin, one block per b ----
__global__ __launch_bounds__(256) void recout_kernel(const float* __restrict__ part,
        const float* __restrict__ lin, float* __restrict__ out0) {
    __shared__ float mrow[256];
    int b = blockIdx.x, tid = threadIdx.x;
    float s = 0.f;
    #pragma unroll
    for (int j = 0; j < 16; ++j) s += part[(size_t)(j * B_DIM + b) * H_DIM + tid];
    mrow[tid] = s * (1.f / T_DIM);
    __syncthreads();
    float acc = 0.f;
    #pragma unroll 8
    for (int h = 0; h < H_DIM; ++h) acc = fmaf(mrow[h], lin[(size_t)h * H_DIM + tid], acc);
    out0[b * H_DIM + tid] = acc;
}

extern "C" void kernel_launch(void* const* d_in, const int* in_sizes, int n_in,
                              void* d_out, int out_size, void* d_ws, size_t ws_size,
                              hipStream_t stream) {
    const float* x = (const float*)d_in[0];
    const float* w = (const float*)d_in[1];
    float* out0 = (float*)d_out;                       // B*H
    float* out1 = out0 + (size_t)B_DIM * H_DIM;        // T*B*H
    float* hxT  = out1 + (size_t)TB * H_DIM;           // B*H*K

    char* ws = (char*)d_ws;
    __hip_bfloat16* wb   = (__hip_bfloat16*)(ws + 0);          // 1,310,720
    __hip_bfloat16* wb2  = (__hip_bfloat16*)(ws + 1310720);    // 1,310,720
    float* xninfo        = (float*)(ws + 2621440);             //   131,072
    float* Mm            = (float*)(ws + 2752512);             //   262,144
    float* rsum          = (float*)(ws + 3014656);             //     1,024
    float* vbuf          = (float*)(ws + 3015680);             //     1,024
    float* cbuf          = (float*)(ws + 3016704);             //     1,024
    float* E2g           = (float*)(ws + 3017728);             //   262,144
    __hip_bfloat16* e2b  = (__hip_bfloat16*)(ws + 3279872);    //   131,072
    float* lin           = (float*)(ws + 3410944);             //   262,144
    __hip_bfloat16* linb = (__hip_bfloat16*)(ws + 3673088);    //   131,072
    float* part          = (float*)(ws + 3804160);             //   524,288 (16 slots)
    float* Mpart         = (float*)(ws + 4328448);             // 4,194,304
    __hip_bfloat16* xb   = (__hip_bfloat16*)(ws + 8522752);    // 8,388,608
    __hip_bfloat16* bmat = (__hip_bfloat16*)(ws + 16911360);   // 83,886,080 -> ~100.8 MB

    prep_kernel<<<dim3(4736), dim3(256), 0, stream>>>(w, x, wb, wb2, xninfo, xb);
    gemm_b_mfma<<<dim3(128, 20), dim3(256), 0, stream>>>(xb, wb, xninfo, bmat);
    gram_partial<<<dim3(2, 2, 16), dim3(256), 0, stream>>>(wb2, Mpart);
    gram_finish<<<dim3(256), dim3(256), 0, stream>>>(Mpart, Mm, rsum);
    power_kernel<<<dim3(1), dim3(512), 0, stream>>>(Mm, rsum, vbuf, cbuf);
    e2_kernel<<<dim3(16), dim3(256), 0, stream>>>(Mm, vbuf, cbuf, E2g, e2b);
    e3lin_kernel<<<dim3(16), dim3(256), 0, stream>>>(Mm, vbuf, cbuf, E2g, e2b, lin, linb);
    megarec2<<<dim3(256), dim3(512), 0, stream>>>(bmat, linb, out1, part, hxT);
    recout_kernel<<<dim3(32), dim3(256), 0, stream>>>(part, lin, out0);
}

// Round 16
// 132.582 us; speedup vs baseline: 1.2732x; 1.0202x over previous
//
#include <hip/hip_runtime.h>
#include <hip/hip_bf16.h>

// Problem dims
#define T_DIM 512
#define B_DIM 32
#define IN_DIM 256
#define H_DIM 256
#define K_DIM 10
#define TB 16384          // T*B
#define NKH 2560          // H*K
#define NPOW 2            // normalized power updates (v0 = rsum = M@1 is already 1 step;
                          // 2 updates -> vec err ~0.18^3 ~ 6e-3 -> Taylor residual < 1e-4)

typedef __attribute__((ext_vector_type(8))) short short8;
typedef __attribute__((ext_vector_type(4))) float f32x4;
typedef __attribute__((ext_vector_type(4), aligned(4))) int int4u;   // 4B-aligned dwordx4

#define GLOBAL_AS __attribute__((address_space(1)))
#define LDS_AS __attribute__((address_space(3)))

__device__ __forceinline__ float wave_sum64(float v) {
    #pragma unroll
    for (int off = 32; off > 0; off >>= 1) v += __shfl_xor(v, off, 64);
    return v;
}

__device__ __forceinline__ float bf_lo(int u) { return __int_as_float(u << 16); }
__device__ __forceinline__ float bf_hi(int u) { return __int_as_float(u & 0xffff0000); }

// ---- prep: weight normalize (blocks 0..639) + x norms/bf16 (blocks 640..4735) ----
// Vectorized: one float4 load + one short4 store per lane (G13).
__global__ __launch_bounds__(256) void prep_kernel(const float* __restrict__ w,
        const float* __restrict__ x, __hip_bfloat16* __restrict__ wb,
        __hip_bfloat16* __restrict__ wb2, float* __restrict__ xninfo,
        __hip_bfloat16* __restrict__ xb) {
    int wv = threadIdx.x >> 6, lane = threadIdx.x & 63;
    if (blockIdx.x < 640) {
        int row = blockIdx.x * 4 + wv;                 // 0..2559  (= h*10+k)
        float4 v = *(const float4*)(w + (size_t)row * IN_DIM + lane * 4);
        float s = v.x * v.x + v.y * v.y + v.z * v.z + v.w * v.w;
        s = wave_sum64(s);
        float inv = 1.f / fmaxf(sqrtf(s), 1e-4f);
        int h = row / K_DIM, k = row % K_DIM;
        __hip_bfloat16 hb[4];
        hb[0] = __float2bfloat16(v.x * inv); hb[1] = __float2bfloat16(v.y * inv);
        hb[2] = __float2bfloat16(v.z * inv); hb[3] = __float2bfloat16(v.w * inv);
        *(short4*)(wb + (size_t)row * IN_DIM + lane * 4) = *(short4*)hb;
        *(short4*)(wb2 + (size_t)h * NKH + k * IN_DIM + lane * 4) = *(short4*)hb;
    } else {
        int row = (blockIdx.x - 640) * 4 + wv;         // 0..16383
        float4 v = *(const float4*)(x + (size_t)row * IN_DIM + lane * 4);
        float s = v.x * v.x + v.y * v.y + v.z * v.z + v.w * v.w;
        s = wave_sum64(s);
        float nrm = sqrtf(s);
        if (lane == 0) { xninfo[2 * row] = nrm; xninfo[2 * row + 1] = 1.f / fmaxf(nrm, 1e-4f); }
        __hip_bfloat16 hb[4];
        hb[0] = __float2bfloat16(v.x); hb[1] = __float2bfloat16(v.y);
        hb[2] = __float2bfloat16(v.z); hb[3] = __float2bfloat16(v.w);
        *(short4*)(xb + (size_t)row * IN_DIM + lane * 4) = *(short4*)hb;
    }
}

// ---- big GEMM via bf16 MFMA, 2-phase double-buffered staging (proven 43.0us) ----
// bmat bf16 [t][b][h*10+k]
__global__ __launch_bounds__(256) void gemm_b_mfma(const __hip_bfloat16* __restrict__ xb,
        const __hip_bfloat16* __restrict__ wb, const float* __restrict__ xninfo,
        __hip_bfloat16* __restrict__ bmat) {
    __shared__ __hip_bfloat16 As[2][4096];   // 2 x [128][32]
    __shared__ __hip_bfloat16 Bs[2][4096];
    int tid = threadIdx.x;
    int wid = tid >> 6, lane = tid & 63;
    int m0 = blockIdx.x * 128, n0 = blockIdx.y * 128;
    int wr = wid >> 1, wc = wid & 1;
    int srow = tid >> 2;
    int scol = (tid & 3) * 8;
    f32x4 acc[4][4] = {};

    const __hip_bfloat16* ga0 = xb + (size_t)(m0 + srow) * IN_DIM + scol;
    const __hip_bfloat16* gb0 = wb + (size_t)(n0 + srow) * IN_DIM + scol;

    #pragma unroll
    for (int half = 0; half < 2; ++half) {
        __builtin_amdgcn_global_load_lds((const GLOBAL_AS void*)(ga0 + half * 64 * IN_DIM),
            (LDS_AS void*)(&As[0][half * 2048 + wid * 512]), 16, 0, 0);
        __builtin_amdgcn_global_load_lds((const GLOBAL_AS void*)(gb0 + half * 64 * IN_DIM),
            (LDS_AS void*)(&Bs[0][half * 2048 + wid * 512]), 16, 0, 0);
    }
    __syncthreads();

    int cur = 0;
    for (int step = 0; step < 8; ++step) {
        if (step < 7) {
            int kbn = (step + 1) * 32;
            #pragma unroll
            for (int half = 0; half < 2; ++half) {
                __builtin_amdgcn_global_load_lds((const GLOBAL_AS void*)(ga0 + half * 64 * IN_DIM + kbn),
                    (LDS_AS void*)(&As[cur ^ 1][half * 2048 + wid * 512]), 16, 0, 0);
                __builtin_amdgcn_global_load_lds((const GLOBAL_AS void*)(gb0 + half * 64 * IN_DIM + kbn),
                    (LDS_AS void*)(&Bs[cur ^ 1][half * 2048 + wid * 512]), 16, 0, 0);
            }
        }
        int seg = (lane >> 4) * 8;
        int rl = lane & 15;
        short8 a[4], b[4];
        #pragma unroll
        for (int m = 0; m < 4; ++m)
            a[m] = *(const short8*)(&As[cur][(wr * 64 + m * 16 + rl) * 32 + seg]);
        #pragma unroll
        for (int n = 0; n < 4; ++n)
            b[n] = *(const short8*)(&Bs[cur][(wc * 64 + n * 16 + rl) * 32 + seg]);
        #pragma unroll
        for (int m = 0; m < 4; ++m)
            #pragma unroll
            for (int n = 0; n < 4; ++n)
                acc[m][n] = __builtin_amdgcn_mfma_f32_16x16x32_bf16(a[m], b[n], acc[m][n], 0, 0, 0);
        __syncthreads();
        cur ^= 1;
    }

    int col_l = lane & 15;
    int rseg = (lane >> 4) * 4;
    #pragma unroll
    for (int m = 0; m < 4; ++m) {
        int rbase = m0 + wr * 64 + m * 16 + rseg;
        float4 q0 = *(const float4*)(xninfo + 2 * rbase);
        float4 q1 = *(const float4*)(xninfo + 2 * rbase + 4);
        float nrm[4] = { q0.x, q0.z, q1.x, q1.z };
        float inv[4] = { q0.y, q0.w, q1.y, q1.w };
        #pragma unroll
        for (int n = 0; n < 4; ++n) {
            int col = n0 + wc * 64 + n * 16 + col_l;     // = h*10+k directly
            #pragma unroll
            for (int j = 0; j < 4; ++j) {
                float bv = nrm[j] * __expf(0.4f * acc[m][n][j] * inv[j] - 0.4f);
                bmat[(size_t)(rbase + j) * NKH + col] = __float2bfloat16(bv);
            }
        }
    }
}

// ---- Gram split-K partial, 2-phase pipeline: Mpart[kz] = wb2[:,kz*160:+160] @ wb2^T ----
__global__ __launch_bounds__(256) void gram_partial(const __hip_bfloat16* __restrict__ wb2,
        float* __restrict__ Mpart) {
    __shared__ __hip_bfloat16 As[2][4096];
    __shared__ __hip_bfloat16 Bs[2][4096];
    int tid = threadIdx.x;
    int wid = tid >> 6, lane = tid & 63;
    int m0 = blockIdx.x * 128, n0 = blockIdx.y * 128;
    int kz = blockIdx.z;
    int wr = wid >> 1, wc = wid & 1;
    int srow = tid >> 2;
    int scol = (tid & 3) * 8;
    f32x4 acc[4][4] = {};

    const __hip_bfloat16* ga0 = wb2 + (size_t)(m0 + srow) * NKH + kz * 160 + scol;
    const __hip_bfloat16* gb0 = wb2 + (size_t)(n0 + srow) * NKH + kz * 160 + scol;

    #pragma unroll
    for (int half = 0; half < 2; ++half) {
        __builtin_amdgcn_global_load_lds((const GLOBAL_AS void*)(ga0 + half * 64 * NKH),
            (LDS_AS void*)(&As[0][half * 2048 + wid * 512]), 16, 0, 0);
        __builtin_amdgcn_global_load_lds((const GLOBAL_AS void*)(gb0 + half * 64 * NKH),
            (LDS_AS void*)(&Bs[0][half * 2048 + wid * 512]), 16, 0, 0);
    }
    __syncthreads();

    int cur = 0;
    for (int ks = 0; ks < 5; ++ks) {
        if (ks < 4) {
            int kbn = (ks + 1) * 32;
            #pragma unroll
            for (int half = 0; half < 2; ++half) {
                __builtin_amdgcn_global_load_lds((const GLOBAL_AS void*)(ga0 + half * 64 * NKH + kbn),
                    (LDS_AS void*)(&As[cur ^ 1][half * 2048 + wid * 512]), 16, 0, 0);
                __builtin_amdgcn_global_load_lds((const GLOBAL_AS void*)(gb0 + half * 64 * NKH + kbn),
                    (LDS_AS void*)(&Bs[cur ^ 1][half * 2048 + wid * 512]), 16, 0, 0);
            }
        }
        int seg = (lane >> 4) * 8;
        int rl = lane & 15;
        short8 a[4], b[4];
        #pragma unroll
        for (int m = 0; m < 4; ++m)
            a[m] = *(const short8*)(&As[cur][(wr * 64 + m * 16 + rl) * 32 + seg]);
        #pragma unroll
        for (int n = 0; n < 4; ++n)
            b[n] = *(const short8*)(&Bs[cur][(wc * 64 + n * 16 + rl) * 32 + seg]);
        #pragma unroll
        for (int m = 0; m < 4; ++m)
            #pragma unroll
            for (int n = 0; n < 4; ++n)
                acc[m][n] = __builtin_amdgcn_mfma_f32_16x16x32_bf16(a[m], b[n], acc[m][n], 0, 0, 0);
        __syncthreads();
        cur ^= 1;
    }

    float* dst = Mpart + (size_t)kz * 65536;
    int col_l = lane & 15;
    int rseg = (lane >> 4) * 4;
    #pragma unroll
    for (int m = 0; m < 4; ++m) {
        int rbase = m0 + wr * 64 + m * 16 + rseg;
        #pragma unroll
        for (int n = 0; n < 4; ++n) {
            int col = n0 + wc * 64 + n * 16 + col_l;
            #pragma unroll
            for (int j = 0; j < 4; ++j)
                dst[(size_t)(rbase + j) * H_DIM + col] = acc[m][n][j];
        }
    }
}

// ---- Gram finish: Mm = exp(0.4*sum_kz Mpart - 4), rsum[row] = row sum ----
__global__ __launch_bounds__(256) void gram_finish(const float* __restrict__ Mpart,
        float* __restrict__ Mm, float* __restrict__ rsum) {
    __shared__ float red[256];
    int r = blockIdx.x, c = threadIdx.x;
    float s = 0.f;
    #pragma unroll
    for (int kz = 0; kz < 16; ++kz)
        s += Mpart[(size_t)kz * 65536 + (size_t)r * H_DIM + c];
    float e = __expf(0.4f * s - 4.0f);
    Mm[(size_t)r * H_DIM + c] = e;
    red[c] = e;
    __syncthreads();
    #pragma unroll
    for (int st = 128; st > 0; st >>= 1) {
        if (c < st) red[c] += red[c + st];
        __syncthreads();
    }
    if (c == 0) rsum[r] = red[0];
}

// ---- standalone power iteration (1 block x 512 thr, row-split): vbuf, cbuf={lam,lam-1,rsqrt-1}
__global__ __launch_bounds__(512) void power_kernel(const float* __restrict__ Mm,
        const float* __restrict__ rsum, float* __restrict__ vbuf, float* __restrict__ cbuf) {
    __shared__ float vv[256];
    __shared__ float yv[256];
    __shared__ float red[512];
    int tid = threadIdx.x;
    if (tid < 256) vv[tid] = rsum[tid];
    __syncthreads();
    for (int it = 0; it <= NPOW; ++it) {
        int col = tid & 255, q = tid >> 8;             // q in {0,1}: 128-row chunks
        const float* mp = Mm + (size_t)q * 128 * 256 + col;
        float p = 0.f;
        #pragma unroll 8
        for (int g = 0; g < 128; ++g) p = fmaf(mp[(size_t)g * 256], vv[q * 128 + g], p);
        red[tid] = p;
        __syncthreads();
        if (it < NPOW) {
            if (tid < 256) {
                float y = red[tid] + red[tid + 256];
                yv[tid] = y;
                red[tid] = y * y;
            }
            __syncthreads();
            #pragma unroll
            for (int st = 128; st > 0; st >>= 1) {
                if (tid < st) red[tid] += red[tid + st];
                __syncthreads();
            }
            float inv = rsqrtf(red[0]);
            if (tid < 256) vv[tid] = yv[tid] * inv;
            __syncthreads();
        } else {
            if (tid < 256) red[tid] = (red[tid] + red[tid + 256]) * vv[tid];  // Rayleigh
            __syncthreads();
            #pragma unroll
            for (int st = 128; st > 0; st >>= 1) {
                if (tid < st) red[tid] += red[tid + st];
                __syncthreads();
            }
            if (tid == 0) {
                float lam = red[0];
                cbuf[0] = lam;
                cbuf[1] = lam - 1.f;
                cbuf[2] = rsqrtf(lam) - 1.f;
            }
        }
    }
    if (tid < 256) vbuf[tid] = vv[tid];
}

// ---- P2: E2 = E @ E, 16 blocks x 64x64 tile; E from Mm + vbuf on the fly ----
__global__ __launch_bounds__(256) void e2_kernel(const float* __restrict__ Mm,
        const float* __restrict__ vbuf, const float* __restrict__ cbuf,
        float* __restrict__ E2g, __hip_bfloat16* __restrict__ e2b) {
    __shared__ __hip_bfloat16 EA[16384];   // [64][256] bf16, row-swizzled
    __shared__ __hip_bfloat16 EC[16384];
    __shared__ float vv[256];
    int tid = threadIdx.x;
    int r0 = (blockIdx.x >> 2) * 64, c0 = (blockIdx.x & 3) * 64;
    float lm1 = cbuf[1];
    if (tid < 256) vv[tid] = vbuf[tid];
    __syncthreads();
    char* pa = (char*)EA;
    char* pc = (char*)EC;
    for (int f = tid; f < 4096; f += 256) {
        int row = f >> 6, c4 = (f & 63) << 2;
        {
            int r = r0 + row;
            float4 mv = *(const float4*)(Mm + (size_t)r * 256 + c4);
            float vr = lm1 * vv[r];
            __hip_bfloat16 hb[4];
            hb[0] = __float2bfloat16(mv.x - ((r == c4 + 0) ? 1.f : 0.f) - vr * vv[c4 + 0]);
            hb[1] = __float2bfloat16(mv.y - ((r == c4 + 1) ? 1.f : 0.f) - vr * vv[c4 + 1]);
            hb[2] = __float2bfloat16(mv.z - ((r == c4 + 2) ? 1.f : 0.f) - vr * vv[c4 + 2]);
            hb[3] = __float2bfloat16(mv.w - ((r == c4 + 3) ? 1.f : 0.f) - vr * vv[c4 + 3]);
            *(short4*)(pa + row * 512 + ((c4 * 2) ^ ((row & 7) << 4))) = *(short4*)hb;
        }
        {
            int r = c0 + row;
            float4 mv = *(const float4*)(Mm + (size_t)r * 256 + c4);
            float vr = lm1 * vv[r];
            __hip_bfloat16 hb[4];
            hb[0] = __float2bfloat16(mv.x - ((r == c4 + 0) ? 1.f : 0.f) - vr * vv[c4 + 0]);
            hb[1] = __float2bfloat16(mv.y - ((r == c4 + 1) ? 1.f : 0.f) - vr * vv[c4 + 1]);
            hb[2] = __float2bfloat16(mv.z - ((r == c4 + 2) ? 1.f : 0.f) - vr * vv[c4 + 2]);
            hb[3] = __float2bfloat16(mv.w - ((r == c4 + 3) ? 1.f : 0.f) - vr * vv[c4 + 3]);
            *(short4*)(pc + row * 512 + ((c4 * 2) ^ ((row & 7) << 4))) = *(short4*)hb;
        }
    }
    __syncthreads();
    int wv = tid >> 6, lane = tid & 63;
    int rl = lane & 15, seg8 = (lane >> 4) * 8;
    f32x4 acc[4] = {};
    for (int kb = 0; kb < 256; kb += 32) {
        int row = wv * 16 + rl;
        short8 a = *(const short8*)(pa + row * 512 + (((kb + seg8) * 2) ^ ((rl & 7) << 4)));
        short8 b[4];
        #pragma unroll
        for (int n = 0; n < 4; ++n) {
            int rowb = n * 16 + rl;
            b[n] = *(const short8*)(pc + rowb * 512 + (((kb + seg8) * 2) ^ ((rl & 7) << 4)));
        }
        #pragma unroll
        for (int n = 0; n < 4; ++n)
            acc[n] = __builtin_amdgcn_mfma_f32_16x16x32_bf16(a, b[n], acc[n], 0, 0, 0);
    }
    int col_l = lane & 15, rseg = (lane >> 4) * 4;
    #pragma unroll
    for (int n = 0; n < 4; ++n) {
        #pragma unroll
        for (int j = 0; j < 4; ++j) {
            int r = r0 + wv * 16 + rseg + j;
            int c = c0 + n * 16 + col_l;
            size_t idx = (size_t)r * 256 + c;
            E2g[idx] = acc[n][j];
            e2b[idx] = __float2bfloat16(acc[n][j]);
        }
    }
}

// ---- P3: E3 = E @ E2; lin = 1.5I - Mm/2 + (lm1/2+lfac) vv^T + 3/8 E2 - 5/16 E3 ----
__global__ __launch_bounds__(256) void e3lin_kernel(const float* __restrict__ Mm,
        const float* __restrict__ vbuf, const float* __restrict__ cbuf,
        const float* __restrict__ E2g, const __hip_bfloat16* __restrict__ e2b,
        float* __restrict__ lin, __hip_bfloat16* __restrict__ linb) {
    __shared__ __hip_bfloat16 EA[16384];   // [64][256] E rows, swizzled
    __shared__ __hip_bfloat16 EC[16384];   // [64][256] E2 rows (symmetric), swizzled
    __shared__ float vv[256];
    int tid = threadIdx.x;
    int r0 = (blockIdx.x >> 2) * 64, c0 = (blockIdx.x & 3) * 64;
    float lm1 = cbuf[1];
    float wfac = 0.5f * cbuf[1] + cbuf[2];
    if (tid < 256) vv[tid] = vbuf[tid];
    __syncthreads();
    char* pa = (char*)EA;
    char* pc = (char*)EC;
    for (int f = tid; f < 4096; f += 256) {
        int row = f >> 6, c4 = (f & 63) << 2;
        int r = r0 + row;
        float4 mv = *(const float4*)(Mm + (size_t)r * 256 + c4);
        float vr = lm1 * vv[r];
        __hip_bfloat16 hb[4];
        hb[0] = __float2bfloat16(mv.x - ((r == c4 + 0) ? 1.f : 0.f) - vr * vv[c4 + 0]);
        hb[1] = __float2bfloat16(mv.y - ((r == c4 + 1) ? 1.f : 0.f) - vr * vv[c4 + 1]);
        hb[2] = __float2bfloat16(mv.z - ((r == c4 + 2) ? 1.f : 0.f) - vr * vv[c4 + 2]);
        hb[3] = __float2bfloat16(mv.w - ((r == c4 + 3) ? 1.f : 0.f) - vr * vv[c4 + 3]);
        *(short4*)(pa + row * 512 + ((c4 * 2) ^ ((row & 7) << 4))) = *(short4*)hb;
    }
    for (int f = tid; f < 2048; f += 256) {
        int row = f >> 5, c8 = (f & 31) << 3;
        short8 v8 = *(const short8*)(e2b + (size_t)(c0 + row) * 256 + c8);
        *(short8*)(pc + row * 512 + ((c8 * 2) ^ ((row & 7) << 4))) = v8;
    }
    __syncthreads();
    int wv = tid >> 6, lane = tid & 63;
    int rl = lane & 15, seg8 = (lane >> 4) * 8;
    f32x4 acc[4] = {};
    for (int kb = 0; kb < 256; kb += 32) {
        int row = wv * 16 + rl;
        short8 a = *(const short8*)(pa + row * 512 + (((kb + seg8) * 2) ^ ((rl & 7) << 4)));
        short8 b[4];
        #pragma unroll
        for (int n = 0; n < 4; ++n) {
            int rowb = n * 16 + rl;
            b[n] = *(const short8*)(pc + rowb * 512 + (((kb + seg8) * 2) ^ ((rl & 7) << 4)));
        }
        #pragma unroll
        for (int n = 0; n < 4; ++n)
            acc[n] = __builtin_amdgcn_mfma_f32_16x16x32_bf16(a, b[n], acc[n], 0, 0, 0);
    }
    int col_l = lane & 15, rseg = (lane >> 4) * 4;
    #pragma unroll
    for (int n = 0; n < 4; ++n) {
        #pragma unroll
        for (int j = 0; j < 4; ++j) {
            int r = r0 + wv * 16 + rseg + j;
            int c = c0 + n * 16 + col_l;
            size_t idx = (size_t)r * 256 + c;
            float lv = ((r == c) ? 1.5f : 0.f) - 0.5f * Mm[idx] + wfac * vv[r] * vv[c]
                     + 0.375f * E2g[idx] - 0.3125f * acc[n][j];
            lin[idx] = lv;
            linb[idx] = __float2bfloat16(lv);
        }
    }
}

// ---- megarec2: 256 blocks x 512 threads; shared-warm-up pairing (1.5x unique HBM) ----
__global__ __launch_bounds__(512) void megarec2(const __hip_bfloat16* __restrict__ bmat,
        const __hip_bfloat16* __restrict__ linb, float* __restrict__ out1,
        float* __restrict__ part, float* __restrict__ hxT) {
    __shared__ __hip_bfloat16 c9t[16384];  // [64][256] bf16, row-swizzled (32 KB)
    int tid = threadIdx.x;
    int sub = tid >> 8;                    // 0 or 1
    int h = tid & 255;
    int s = blockIdx.x >> 5;               // 0..7
    int b = blockIdx.x & 31;
    int tout0 = s * 64;
    int start = tout0 + sub * 32;
    int t0 = (start == 0) ? 0 : start - 32;
    int t1 = start + 32;
    char* c9p = (char*)c9t;
    float c[10] = {};
    float s9 = 0.f;
    int4u v0; int v1;
    {
        const char* bp = (const char*)bmat + ((size_t)(t0 * B_DIM + b) * NKH + h * 10) * 2;
        v0 = *(const int4u*)bp;
        v1 = *(const int*)(bp + 16);
    }
    for (int t = t0; t < t1; ++t) {
        int tn = (t + 1 < t1) ? t + 1 : t;
        const char* bq = (const char*)bmat + ((size_t)(tn * B_DIM + b) * NKH + h * 10) * 2;
        int4u w0 = *(const int4u*)bq;
        int w1 = *(const int*)(bq + 16);
        float bt[10];
        bt[0] = bf_lo(v0.x); bt[1] = bf_hi(v0.x);
        bt[2] = bf_lo(v0.y); bt[3] = bf_hi(v0.y);
        bt[4] = bf_lo(v0.z); bt[5] = bf_hi(v0.z);
        bt[6] = bf_lo(v0.w); bt[7] = bf_hi(v0.w);
        bt[8] = bf_lo(v1);   bt[9] = bf_hi(v1);
        #pragma unroll
        for (int j = 9; j >= 1; --j) c[j] = 0.5f * c[j] + c[j - 1] * bt[j];
        c[0] = 0.5f * c[0] + bt[0];
        if (t >= start) {
            int tt = t - tout0;            // sub0: 0..31, sub1: 32..63
            *(__hip_bfloat16*)(c9p + tt * 512 + ((h * 2) ^ ((tt & 7) << 4))) = __float2bfloat16(c[9]);
            s9 += c[9];
        }
        v0 = w0; v1 = w1;
    }
    part[(size_t)((s * 2 + sub) * B_DIM + b) * H_DIM + h] = s9;
    if (s == 7 && sub == 1) {
        float* hp = hxT + (size_t)(b * H_DIM + h) * K_DIM;
        #pragma unroll
        for (int k = 0; k < 10; ++k) hp[k] = c[k];
    }
    __syncthreads();
    int wid = tid >> 6, lane = tid & 63;
    int rl = lane & 15, seg8 = (lane >> 4) * 8;
    int col_l = lane & 15, rseg = (lane >> 4) * 4;
    f32x4 acc[4][2] = {};
    for (int kb = 0; kb < 256; kb += 32) {
        short8 a[4];
        #pragma unroll
        for (int m = 0; m < 4; ++m) {
            int row = m * 16 + rl;
            a[m] = *(const short8*)(c9p + row * 512 + (((kb + seg8) * 2) ^ ((row & 7) << 4)));
        }
        short8 bf[2];
        #pragma unroll
        for (int n = 0; n < 2; ++n)
            bf[n] = *(const short8*)(linb + (size_t)(wid * 32 + n * 16 + rl) * 256 + kb + seg8);
        #pragma unroll
        for (int m = 0; m < 4; ++m)
            #pragma unroll
            for (int n = 0; n < 2; ++n)
                acc[m][n] = __builtin_amdgcn_mfma_f32_16x16x32_bf16(a[m], bf[n], acc[m][n], 0, 0, 0);
    }
    #pragma unroll
    for (int m = 0; m < 4; ++m) {
        #pragma unroll
        for (int n = 0; n < 2; ++n) {
            int g = wid * 32 + n * 16 + col_l;
            #pragma unroll
            for (int j = 0; j < 4; ++j) {
                int tt = m * 16 + rseg + j;
                out1[((size_t)(tout0 + tt) * B_DIM + b) * H_DIM + g] = acc[m][n][j];
            }
        }
    }
}

// ---- recout: mean over T of c9 (from part) then out0 = mean @ lin, one block per b ----
__global__ __launch_bounds__(256) void recout_kernel(const float* __restrict__ part,
        const float* __restrict__ lin, float* __restrict__ out0) {
    __shared__ float mrow[256];
    int b = blockIdx.x, tid = threadIdx.x;
    float s = 0.f;
    #pragma unroll
    for (int j = 0; j < 16; ++j) s += part[(size_t)(j * B_DIM + b) * H_DIM + tid];
    mrow[tid] = s * (1.f / T_DIM);
    __syncthreads();
    float acc = 0.f;
    #pragma unroll 8
    for (int h = 0; h < H_DIM; ++h) acc = fmaf(mrow[h], lin[(size_t)h * H_DIM + tid], acc);
    out0[b * H_DIM + tid] = acc;
}

extern "C" void kernel_launch(void* const* d_in, const int* in_sizes, int n_in,
                              void* d_out, int out_size, void* d_ws, size_t ws_size,
                              hipStream_t stream) {
    const float* x = (const float*)d_in[0];
    const float* w = (const float*)d_in[1];
    float* out0 = (float*)d_out;                       // B*H
    float* out1 = out0 + (size_t)B_DIM * H_DIM;        // T*B*H
    float* hxT  = out1 + (size_t)TB * H_DIM;           // B*H*K

    char* ws = (char*)d_ws;
    __hip_bfloat16* wb   = (__hip_bfloat16*)(ws + 0);          // 1,310,720
    __hip_bfloat16* wb2  = (__hip_bfloat16*)(ws + 1310720);    // 1,310,720
    float* xninfo        = (float*)(ws + 2621440);             //   131,072
    float* Mm            = (float*)(ws + 2752512);             //   262,144
    float* rsum          = (float*)(ws + 3014656);             //     1,024
    float* vbuf          = (float*)(ws + 3015680);             //     1,024
    float* cbuf          = (float*)(ws + 3016704);             //     1,024
    float* E2g           = (float*)(ws + 3017728);             //   262,144
    __hip_bfloat16* e2b  = (__hip_bfloat16*)(ws + 3279872);    //   131,072
    float* lin           = (float*)(ws + 3410944);             //   262,144
    __hip_bfloat16* linb = (__hip_bfloat16*)(ws + 3673088);    //   131,072
    float* part          = (float*)(ws + 3804160);             //   524,288 (16 slots)
    float* Mpart         = (float*)(ws + 4328448);             // 4,194,304
    __hip_bfloat16* xb   = (__hip_bfloat16*)(ws + 8522752);    // 8,388,608
    __hip_bfloat16* bmat = (__hip_bfloat16*)(ws + 16911360);   // 83,886,080 -> ~100.8 MB

    prep_kernel<<<dim3(4736), dim3(256), 0, stream>>>(w, x, wb, wb2, xninfo, xb);
    gemm_b_mfma<<<dim3(128, 20), dim3(256), 0, stream>>>(xb, wb, xninfo, bmat);
    gram_partial<<<dim3(2, 2, 16), dim3(256), 0, stream>>>(wb2, Mpart);
    gram_finish<<<dim3(256), dim3(256), 0, stream>>>(Mpart, Mm, rsum);
    power_kernel<<<dim3(1), dim3(512), 0, stream>>>(Mm, rsum, vbuf, cbuf);
    e2_kernel<<<dim3(16), dim3(256), 0, stream>>>(Mm, vbuf, cbuf, E2g, e2b);
    e3lin_kernel<<<dim3(16), dim3(256), 0, stream>>>(Mm, vbuf, cbuf, E2g, e2b, lin, linb);
    megarec2<<<dim3(256), dim3(512), 0, stream>>>(bmat, linb, out1, part, hxT);
    recout_kernel<<<dim3(32), dim3(256), 0, stream>>>(part, lin, out0);
}